// Round 22
// baseline (140.704 us; speedup 1.0000x reference)
//
#include <hip/hip_runtime.h>
#include <math.h>

// Problem constants
constexpr int BATCH = 16384;
constexpr int IND   = 2048;   // INPUT
constexpr int HID   = 32;     // HIDDEN
constexpr int OUTD  = 512;    // OUTPUT

constexpr int NC1 = 64;       // corr1/xsum partial slices (b-chunks of 256)
constexpr int NSA = 512;      // actsum partial slices (k_act blocks)
constexpr int NC2 = 128;      // corr2/outsum partial slices (b-chunks of 128)

constexpr int SA   = 136;     // ushort row stride, k_act tiles
constexpr int SXT  = 72;      // ushort row stride, k_corr1 xT tile (64 b)
constexpr int SATW = 136;     // ushort row stride, k_fwd2m actT tile (128 b)
constexpr int SAT2 = 264;     // ushort row stride, k_corr1 actT tile (256 b)

typedef __attribute__((ext_vector_type(8))) short bf16x8;
typedef __attribute__((ext_vector_type(4))) float f32x4;

__device__ __forceinline__ unsigned short f2bf(float f) {
  unsigned u = __float_as_uint(f);
  u += 0x7FFFu + ((u >> 16) & 1u);          // round-to-nearest-even
  return (unsigned short)(u >> 16);
}
__device__ __forceinline__ float bf2f(unsigned short h) {
  return __uint_as_float(((unsigned)h) << 16);
}
__device__ __forceinline__ void split2(float f, unsigned short& hi,
                                       unsigned short& lo) {
  hi = f2bf(f);
  lo = f2bf(f - bf2f(hi));
}
__device__ __forceinline__ int swzA(int row, int col) {
  return row * SA + (col ^ (((row >> 3) & 7) * 8));
}

// ---------------------------------------------------------------------------
// K0: pre-split w1/w2 to hi/lo bf16 once (r19-verified).
// ---------------------------------------------------------------------------
__global__ __launch_bounds__(256) void k_cvtw(
    const float* __restrict__ w1, const float* __restrict__ w2,
    unsigned short* __restrict__ w1H, unsigned short* __restrict__ w1L,
    unsigned short* __restrict__ w2H, unsigned short* __restrict__ w2L) {
  const int bid = blockIdx.x;
  if (bid < 64) {
    const int g = bid * 256 + threadIdx.x;          // < 16384
    float4 v = ((const float4*)w1)[g];
    ushort4 h, l;
    split2(v.x, h.x, l.x); split2(v.y, h.y, l.y);
    split2(v.z, h.z, l.z); split2(v.w, h.w, l.w);
    ((ushort4*)w1H)[g] = h;
    ((ushort4*)w1L)[g] = l;
  } else {
    const int g = (bid - 64) * 256 + threadIdx.x;   // < 4096
    float4 v = ((const float4*)w2)[g];
    ushort4 h, l;
    split2(v.x, h.x, l.x); split2(v.y, h.y, l.y);
    split2(v.z, h.z, l.z); split2(v.w, h.w, l.w);
    ((ushort4*)w2H)[g] = h;
    ((ushort4*)w2L)[g] = l;
  }
}

// ---------------------------------------------------------------------------
// K1: FUSED act kernel. Full K per block (no split) -> full sums in regs ->
// relu + actH/actL [b][h] + actT [h][b] + actsum partials emitted directly.
// Kills the act_part round trip (16.8 MB x2) and the k_actc launch (r21's
// only remaining self-inflicted traffic). Also emits xH bf16 [b][k].
// grid = 512 (bt x 32 rows); (256,4); 35.8KB LDS.
// ---------------------------------------------------------------------------
__global__ __launch_bounds__(256, 4) void k_act(
    const float* __restrict__ x, const unsigned short* __restrict__ w1H,
    const unsigned short* __restrict__ w1L, unsigned short* __restrict__ xH,
    unsigned short* __restrict__ actH, unsigned short* __restrict__ actL,
    unsigned short* __restrict__ actT, float* __restrict__ actsum_part) {
  const int tid = threadIdx.x;
  const int bt = blockIdx.x;               // 0..511
  const int b0 = bt * 32;
  const int lane = tid & 63;
  const int wv = tid >> 6;                 // 0..3
  const int arow = lane & 15;
  const int m4 = lane >> 4;                // 0..3
  const int ksub = m4 * 8;
  const int rt = wv & 1;
  const int ht = wv >> 1;

  __shared__ __align__(16) unsigned short XHs[32 * SA];
  __shared__ __align__(16) unsigned short XLs[32 * SA];
  __shared__ __align__(16) unsigned short WHs[32 * SA];
  __shared__ __align__(16) unsigned short WLs[32 * SA];
  __shared__ float asum_s[32][8];

  const int rp = tid >> 4;
  const int kg = (tid & 15) * 8;

  float4 px0a, px0b, px1a, px1b;
  bf16x8 pwh0, pwl0, pwh1, pwl1;

#define LOADA(K0)                                                          \
  {                                                                        \
    const float* xr0 = x + (size_t)(b0 + 2 * rp) * IND + (K0) + kg;        \
    const float* xr1 = xr0 + IND;                                          \
    px0a = *(const float4*)(xr0);                                          \
    px0b = *(const float4*)(xr0 + 4);                                      \
    px1a = *(const float4*)(xr1);                                          \
    px1b = *(const float4*)(xr1 + 4);                                      \
    const size_t wo = (size_t)(2 * rp) * IND + (K0) + kg;                  \
    pwh0 = *(const bf16x8*)(&w1H[wo]);                                     \
    pwl0 = *(const bf16x8*)(&w1L[wo]);                                     \
    pwh1 = *(const bf16x8*)(&w1H[wo + IND]);                               \
    pwl1 = *(const bf16x8*)(&w1L[wo + IND]);                               \
  }

#define PUTX2(ROW, COL, V, GK)                                       \
  {                                                                  \
    ushort4 h_, l_;                                                  \
    split2((V).x, h_.x, l_.x); split2((V).y, h_.y, l_.y);            \
    split2((V).z, h_.z, l_.z); split2((V).w, h_.w, l_.w);            \
    *(ushort4*)(&XHs[swzA((ROW), (COL))]) = h_;                      \
    *(ushort4*)(&XLs[swzA((ROW), (COL))]) = l_;                      \
    *(ushort4*)(&xH[(size_t)(b0 + (ROW)) * IND + (GK) + (COL)]) = h_;\
  }

#define STOREA(GK)                                                   \
  {                                                                  \
    PUTX2(2 * rp, kg, px0a, GK);                                     \
    PUTX2(2 * rp, kg + 4, px0b, GK);                                 \
    PUTX2(2 * rp + 1, kg, px1a, GK);                                 \
    PUTX2(2 * rp + 1, kg + 4, px1b, GK);                             \
    *(bf16x8*)(&WHs[swzA(2 * rp, kg)]) = pwh0;                       \
    *(bf16x8*)(&WLs[swzA(2 * rp, kg)]) = pwl0;                       \
    *(bf16x8*)(&WHs[swzA(2 * rp + 1, kg)]) = pwh1;                   \
    *(bf16x8*)(&WLs[swzA(2 * rp + 1, kg)]) = pwl1;                   \
  }

  f32x4 accA = {0.f, 0.f, 0.f, 0.f};
  LOADA(0);

  for (int kc = 0; kc < 16; ++kc) {
    __syncthreads();
    STOREA(kc * 128);
    __syncthreads();
    if (kc < 15) LOADA((kc + 1) * 128);
    const int xrow = rt * 16 + arow;
    const int wrow = ht * 16 + arow;
#pragma unroll
    for (int ks = 0; ks < 4; ++ks) {
      const int kk = ks * 32 + ksub;
      bf16x8 ah = *(const bf16x8*)(&XHs[swzA(xrow, kk)]);
      bf16x8 al = *(const bf16x8*)(&XLs[swzA(xrow, kk)]);
      bf16x8 bh = *(const bf16x8*)(&WHs[swzA(wrow, kk)]);
      bf16x8 bl_ = *(const bf16x8*)(&WLs[swzA(wrow, kk)]);
      accA = __builtin_amdgcn_mfma_f32_16x16x32_bf16(ah, bh, accA, 0, 0, 0);
      accA = __builtin_amdgcn_mfma_f32_16x16x32_bf16(ah, bl_, accA, 0, 0, 0);
      accA = __builtin_amdgcn_mfma_f32_16x16x32_bf16(al, bh, accA, 0, 0, 0);
    }
  }

  // relu + epilogue (fused from old k_actc)
#pragma unroll
  for (int r = 0; r < 4; ++r) accA[r] = fmaxf(accA[r], 0.f);

  const int bl = rt * 16 + (m4 << 2);      // local b of reg 0
  const int h = ht * 16 + arow;            // global h
  ushort4 hh4, ll4;
  {
    unsigned short h0_, l0_, h1_, l1_, h2_, l2_, h3_, l3_;
    split2(accA[0], h0_, l0_);
    split2(accA[1], h1_, l1_);
    split2(accA[2], h2_, l2_);
    split2(accA[3], h3_, l3_);
    hh4.x = h0_; hh4.y = h1_; hh4.z = h2_; hh4.w = h3_;
    ll4.x = l0_; ll4.y = l1_; ll4.z = l2_; ll4.w = l3_;
  }
  // actH/actL [b][h]: 4 scalar stores each (stride HID)
#pragma unroll
  for (int r = 0; r < 4; ++r) {
    actH[(size_t)(b0 + bl + r) * HID + h] = (&hh4.x)[r];
    actL[(size_t)(b0 + bl + r) * HID + h] = (&ll4.x)[r];
  }
  // actT [h][b]: contiguous over b -> one ushort4 store
  *(ushort4*)(&actT[(size_t)h * BATCH + b0 + bl]) = hh4;

  // actsum partial
  asum_s[h][rt * 4 + m4] = accA[0] + accA[1] + accA[2] + accA[3];
  __syncthreads();
  if (tid < 32) {
    float s = 0.f;
#pragma unroll
    for (int q = 0; q < 8; ++q) s += asum_s[tid][q];
    actsum_part[bt * HID + tid] = s;
  }
}

// ---------------------------------------------------------------------------
// K1c: corr1T_part = x^T @ act (+ xsum via ones tile), reading xH bf16.
// 256-b chunks, C-reg accumulation over 4 halves (r21-verified).
// grid = 1024 = (bc 0..63 x 256 b) x (iq 0..15 x 128 i); 512 thr, (512,3).
// ---------------------------------------------------------------------------
__global__ __launch_bounds__(512, 3) void k_corr1(
    const unsigned short* __restrict__ xH,
    const unsigned short* __restrict__ actT,
    float* __restrict__ corr1T_part, float* __restrict__ xsum_part) {
  const int tid = threadIdx.x;
  const int bc = blockIdx.x >> 4;          // 0..63
  const int iq = blockIdx.x & 15;          // 0..15
  const int b0 = bc * 256;
  const int ibase = iq * 128;
  const int lane = tid & 63;
  const int wv = tid >> 6;                 // 0..7
  const int arow = lane & 15;
  const int m4 = lane >> 4;
  const int ksub = m4 * 8;
  const int it = wv * 16;                  // wave's i-tile base (0..112)

  __shared__ __align__(16) unsigned short XT[128 * SXT];   // [128 i][64 b]
  __shared__ __align__(16) unsigned short AT[48 * SAT2];   // [48][256 b]

  for (int e = tid; e < 16 * SAT2; e += 512)
    AT[32 * SAT2 + e] = (unsigned short)0x3F80;
  {
    const int hrow = tid >> 4;             // 0..31
    const int sg = (tid & 15) * 16;        // 0..240
    const int sw = ((hrow >> 3) & 7) * 8;
#pragma unroll
    for (int j = 0; j < 2; ++j) {
      const int boff = sg + 8 * j;
      bf16x8 v = *(const bf16x8*)(&actT[(size_t)hrow * BATCH + b0 + boff]);
      *(bf16x8*)(&AT[hrow * SAT2 + (boff ^ sw)]) = v;
    }
  }

  const int ig = tid & 15;                 // i-group (8 i)
  const int bq = tid >> 4;                 // 0..31 -> half-local rows 2bq,2bq+1

  bf16x8 xa, ya;

#define LOADC(HF)                                                           \
  {                                                                         \
    const int icol = ibase + ig * 8;                                        \
    const unsigned short* r0 =                                              \
        xH + (size_t)(b0 + 64 * (HF) + 2 * bq) * IND + icol;                \
    xa = *(const bf16x8*)(r0);                                              \
    ya = *(const bf16x8*)(r0 + IND);                                        \
  }

#define STC                                                                 \
  {                                                                         \
    const int qb = (2 * bq) ^ ((ig & 7) * 8);                               \
    unsigned short* basew = &XT[(size_t)(ig * 8) * SXT + qb];               \
    ushort2 p;                                                              \
    p.x = (unsigned short)xa[0]; p.y = (unsigned short)ya[0];               \
    *(ushort2*)(basew + 0 * SXT) = p;                                       \
    p.x = (unsigned short)xa[1]; p.y = (unsigned short)ya[1];               \
    *(ushort2*)(basew + 1 * SXT) = p;                                       \
    p.x = (unsigned short)xa[2]; p.y = (unsigned short)ya[2];               \
    *(ushort2*)(basew + 2 * SXT) = p;                                       \
    p.x = (unsigned short)xa[3]; p.y = (unsigned short)ya[3];               \
    *(ushort2*)(basew + 3 * SXT) = p;                                       \
    p.x = (unsigned short)xa[4]; p.y = (unsigned short)ya[4];               \
    *(ushort2*)(basew + 4 * SXT) = p;                                       \
    p.x = (unsigned short)xa[5]; p.y = (unsigned short)ya[5];               \
    *(ushort2*)(basew + 5 * SXT) = p;                                       \
    p.x = (unsigned short)xa[6]; p.y = (unsigned short)ya[6];               \
    *(ushort2*)(basew + 6 * SXT) = p;                                       \
    p.x = (unsigned short)xa[7]; p.y = (unsigned short)ya[7];               \
    *(ushort2*)(basew + 7 * SXT) = p;                                       \
  }

  const int swzr = (((it + arow) >> 3) & 7) * 8;
  const int swze0 = ((arow >> 3) & 7) * 8;
  const int swze1 = (((16 + arow) >> 3) & 7) * 8;

  f32x4 c00 = {0.f, 0.f, 0.f, 0.f};
  f32x4 c01 = {0.f, 0.f, 0.f, 0.f};
  f32x4 c02 = {0.f, 0.f, 0.f, 0.f};

  LOADC(0);
#pragma unroll
  for (int hf = 0; hf < 4; ++hf) {
    __syncthreads();
    STC;
    __syncthreads();
    if (hf < 3) LOADC(hf + 1);
#pragma unroll
    for (int bs = 0; bs < 2; ++bs) {
      const int bb = bs * 32 + ksub;
      const int bb2 = 64 * hf + bb;
      bf16x8 a = *(const bf16x8*)(&XT[(it + arow) * SXT + (bb ^ swzr)]);
      bf16x8 e0 = *(const bf16x8*)(&AT[arow * SAT2 + (bb2 ^ swze0)]);
      bf16x8 e1 = *(const bf16x8*)(&AT[(16 + arow) * SAT2 + (bb2 ^ swze1)]);
      bf16x8 e2 = *(const bf16x8*)(&AT[(32 + arow) * SAT2 + bb2]);
      c00 = __builtin_amdgcn_mfma_f32_16x16x32_bf16(a, e0, c00, 0, 0, 0);
      c01 = __builtin_amdgcn_mfma_f32_16x16x32_bf16(a, e1, c01, 0, 0, 0);
      c02 = __builtin_amdgcn_mfma_f32_16x16x32_bf16(a, e2, c02, 0, 0, 0);
    }
  }

  float* basep = corr1T_part + (size_t)bc * (IND * HID);
  const int gi = ibase + it + (m4 << 2);
  *(f32x4*)(basep + (size_t)arow * IND + gi) = c00;
  *(f32x4*)(basep + (size_t)(16 + arow) * IND + gi) = c01;
  if (arow == 0)
    *(f32x4*)(xsum_part + (size_t)bc * IND + gi) = c02;
}

// ---------------------------------------------------------------------------
// K1d: deterministic reduce (corr1T/xsum: 64 slices, actsum: 512).
// ---------------------------------------------------------------------------
__global__ __launch_bounds__(256) void k_red1(
    const float* __restrict__ c1p, const float* __restrict__ xsp,
    const float* __restrict__ asp,
    float* __restrict__ corr1T, float* __restrict__ xsum,
    float* __restrict__ actsum) {
  const int e = blockIdx.x * 256 + threadIdx.x;
  float s = 0.f;
#pragma unroll 8
  for (int c = 0; c < NC1; ++c) s += c1p[(size_t)c * (IND * HID) + e];
  corr1T[e] = s;
  if (e < IND) {
    float t = 0.f;
#pragma unroll 8
    for (int c = 0; c < NC1; ++c) t += xsp[(size_t)c * IND + e];
    xsum[e] = t;
  }
  if (e < HID) {
    float t = 0.f;
#pragma unroll 8
    for (int c = 0; c < NSA; ++c) t += asp[(size_t)c * HID + e];
    actsum[e] = t;
  }
}

// ---------------------------------------------------------------------------
// K3: layer-2 MFMA, 128-b blocks, C-reg accumulation (r20-verified).
// grid = 512 = (bc 0..127) x (og 0..3); 256 thr.
// ---------------------------------------------------------------------------
__global__ __launch_bounds__(256, 2) void k_fwd2m(
    const unsigned short* __restrict__ actH,
    const unsigned short* __restrict__ actL,
    const unsigned short* __restrict__ actT,
    const unsigned short* __restrict__ w2H,
    const unsigned short* __restrict__ w2L,
    float* __restrict__ out, float* __restrict__ corr2_part,
    float* __restrict__ outsum_part) {
  const int tid = threadIdx.x;
  const int bc = blockIdx.x >> 2;          // 0..127
  const int og = blockIdx.x & 3;           // 0..3
  const int b0 = bc * 128;
  const int obase = og * 128;
  const int lane = tid & 63;
  const int wv = tid >> 6;                 // 0..3
  const int arow = lane & 15;
  const int m4 = lane >> 4;
  const int ksub = m4 * 8;

  __shared__ __align__(16) unsigned short W2Hs[128 * 40];
  __shared__ __align__(16) unsigned short W2Ls[128 * 40];
  __shared__ __align__(16) unsigned short AH[64 * 40];
  __shared__ __align__(16) unsigned short AL[64 * 40];
  __shared__ __align__(16) unsigned short AT[48 * SATW];
  __shared__ __align__(16) unsigned short OT[128 * 72];

  {
    const int r2 = tid >> 1, hh = (tid & 1) * 16;
    const size_t wo = (size_t)(obase + r2) * HID + hh;
    *(bf16x8*)(&W2Hs[r2 * 40 + hh]) = *(const bf16x8*)(&w2H[wo]);
    *(bf16x8*)(&W2Hs[r2 * 40 + hh + 8]) = *(const bf16x8*)(&w2H[wo + 8]);
    *(bf16x8*)(&W2Ls[r2 * 40 + hh]) = *(const bf16x8*)(&w2L[wo]);
    *(bf16x8*)(&W2Ls[r2 * 40 + hh + 8]) = *(const bf16x8*)(&w2L[wo + 8]);
  }
  {
    const int h = tid >> 3, seg16 = (tid & 7) * 16;
#pragma unroll
    for (int j = 0; j < 2; ++j) {
      const int seg = seg16 + 8 * j;
      *(bf16x8*)(&AT[h * SATW + seg]) =
          *(const bf16x8*)(&actT[(size_t)h * BATCH + b0 + seg]);
    }
  }
  for (int e = tid; e < 16 * SATW; e += 256)
    AT[32 * SATW + e] = (unsigned short)0x3F80;

  f32x4 c0a = {0.f,0.f,0.f,0.f}, c1a = {0.f,0.f,0.f,0.f}, c2a = {0.f,0.f,0.f,0.f};
  f32x4 c0b = {0.f,0.f,0.f,0.f}, c1b = {0.f,0.f,0.f,0.f}, c2b = {0.f,0.f,0.f,0.f};

  for (int hf = 0; hf < 2; ++hf) {
    __syncthreads();
    {
      const int b = tid >> 2, q = (tid & 3) * 8;
      *(bf16x8*)(&AH[b * 40 + q]) =
          *(const bf16x8*)(&actH[(size_t)(b0 + 64 * hf + b) * HID + q]);
      *(bf16x8*)(&AL[b * 40 + q]) =
          *(const bf16x8*)(&actL[(size_t)(b0 + 64 * hf + b) * HID + q]);
    }
    __syncthreads();

    const int bt = wv;
    bf16x8 fah = *(const bf16x8*)(&AH[(bt * 16 + arow) * 40 + ksub]);
    bf16x8 fal = *(const bf16x8*)(&AL[(bt * 16 + arow) * 40 + ksub]);
#pragma unroll
    for (int ot = 0; ot < 8; ++ot) {
      bf16x8 wbh = *(const bf16x8*)(&W2Hs[(ot * 16 + arow) * 40 + ksub]);
      bf16x8 wbl = *(const bf16x8*)(&W2Ls[(ot * 16 + arow) * 40 + ksub]);
      f32x4 z = {0.f, 0.f, 0.f, 0.f};
      z = __builtin_amdgcn_mfma_f32_16x16x32_bf16(fah, wbh, z, 0, 0, 0);
      z = __builtin_amdgcn_mfma_f32_16x16x32_bf16(fah, wbl, z, 0, 0, 0);
      z = __builtin_amdgcn_mfma_f32_16x16x32_bf16(fal, wbh, z, 0, 0, 0);
      ushort4 po;
      {
        float ov0 = 1.0f / (1.0f + __expf(-z[0])) - 0.4f;
        float ov1 = 1.0f / (1.0f + __expf(-z[1])) - 0.4f;
        float ov2 = 1.0f / (1.0f + __expf(-z[2])) - 0.4f;
        float ov3 = 1.0f / (1.0f + __expf(-z[3])) - 0.4f;
        const size_t ob = (size_t)(b0 + 64 * hf + bt * 16 + m4 * 4) * OUTD +
                          obase + ot * 16 + arow;
        out[ob + 0 * OUTD] = ov0;
        out[ob + 1 * OUTD] = ov1;
        out[ob + 2 * OUTD] = ov2;
        out[ob + 3 * OUTD] = ov3;
        po.x = f2bf(ov0); po.y = f2bf(ov1); po.z = f2bf(ov2); po.w = f2bf(ov3);
      }
      *(ushort4*)(&OT[(ot * 16 + arow) * 72 + bt * 16 + m4 * 4]) = po;
    }
    __syncthreads();

    {
      const int ot = wv * 2;
#pragma unroll
      for (int ks = 0; ks < 2; ++ks) {
        const int bb = ks * 32 + ksub;
        const int bb2 = 64 * hf + bb;
        bf16x8 bo = *(const bf16x8*)(&OT[(ot * 16 + arow) * 72 + bb]);
        bf16x8 a0 = *(const bf16x8*)(&AT[arow * SATW + bb2]);
        bf16x8 a1 = *(const bf16x8*)(&AT[(16 + arow) * SATW + bb2]);
        bf16x8 a2 = *(const bf16x8*)(&AT[(32 + arow) * SATW + bb2]);
        c0a = __builtin_amdgcn_mfma_f32_16x16x32_bf16(a0, bo, c0a, 0, 0, 0);
        c1a = __builtin_amdgcn_mfma_f32_16x16x32_bf16(a1, bo, c1a, 0, 0, 0);
        c2a = __builtin_amdgcn_mfma_f32_16x16x32_bf16(a2, bo, c2a, 0, 0, 0);
      }
    }
    {
      const int ot = wv * 2 + 1;
#pragma unroll
      for (int ks = 0; ks < 2; ++ks) {
        const int bb = ks * 32 + ksub;
        const int bb2 = 64 * hf + bb;
        bf16x8 bo = *(const bf16x8*)(&OT[(ot * 16 + arow) * 72 + bb]);
        bf16x8 a0 = *(const bf16x8*)(&AT[arow * SATW + bb2]);
        bf16x8 a1 = *(const bf16x8*)(&AT[(16 + arow) * SATW + bb2]);
        bf16x8 a2 = *(const bf16x8*)(&AT[(32 + arow) * SATW + bb2]);
        c0b = __builtin_amdgcn_mfma_f32_16x16x32_bf16(a0, bo, c0b, 0, 0, 0);
        c1b = __builtin_amdgcn_mfma_f32_16x16x32_bf16(a1, bo, c1b, 0, 0, 0);
        c2b = __builtin_amdgcn_mfma_f32_16x16x32_bf16(a2, bo, c2b, 0, 0, 0);
      }
    }
  }

  {
    const int ot0 = wv * 2, ot1 = wv * 2 + 1;
    float* cp0 = corr2_part + (size_t)bc * (HID * OUTD) + obase + ot0 * 16 + arow;
    float* cp1 = corr2_part + (size_t)bc * (HID * OUTD) + obase + ot1 * 16 + arow;
#pragma unroll
    for (int r = 0; r < 4; ++r) {
      cp0[(size_t)(m4 * 4 + r) * OUTD] = c0a[r];
      cp0[(size_t)(16 + m4 * 4 + r) * OUTD] = c1a[r];
      cp1[(size_t)(m4 * 4 + r) * OUTD] = c0b[r];
      cp1[(size_t)(16 + m4 * 4 + r) * OUTD] = c1b[r];
    }
    if (m4 == 0) {
      outsum_part[(size_t)bc * OUTD + obase + ot0 * 16 + arow] = c2a[0];
      outsum_part[(size_t)bc * OUTD + obase + ot1 * 16 + arow] = c2b[0];
    }
  }
}

// ---------------------------------------------------------------------------
// K3b: deterministic reduce of corr2/outsum partials (128 slices).
// ---------------------------------------------------------------------------
__global__ __launch_bounds__(256) void k_red2(
    const float* __restrict__ corr2_part, const float* __restrict__ outsum_part,
    float* __restrict__ corr2, float* __restrict__ outsum) {
  const int e = blockIdx.x * 256 + threadIdx.x;
  float s = 0.f;
#pragma unroll 8
  for (int c = 0; c < NC2; ++c) s += corr2_part[(size_t)c * (HID * OUTD) + e];
  corr2[e] = s;
  if (e < OUTD) {
    float t = 0.f;
#pragma unroll 8
    for (int c = 0; c < NC2; ++c) t += outsum_part[(size_t)c * OUTD + e];
    outsum[e] = t;
  }
}

// ---------------------------------------------------------------------------
// K4: w1_new[h,i] = (w1[h,i] + dw1T[i,h]) / ||row h||_2 ; corr1T[h][i].
// ---------------------------------------------------------------------------
__global__ __launch_bounds__(256) void k_w1(
    const float* __restrict__ w1, const float* __restrict__ heb,
    const float* __restrict__ corr1T, const float* __restrict__ xsum,
    const float* __restrict__ actsum, float* __restrict__ w1out) {
  const int h = blockIdx.x;
  const int tid = threadIdx.x;
  const float ash = actsum[h];
  const float4* heb4 = (const float4*)heb;

  float val[8];
  float ss = 0.f;
#pragma unroll
  for (int r = 0; r < 8; ++r) {
    const int i = tid + 256 * r;
    float4 c = heb4[(size_t)i * HID + h];
    float v = w1[(size_t)h * IND + i] + 16384.0f * c.w +
              c.x * corr1T[(size_t)h * IND + i] + c.y * xsum[i] + c.z * ash;
    val[r] = v;
    ss += v * v;
  }

  __shared__ float red[256];
  red[tid] = ss;
  __syncthreads();
  for (int s = 128; s > 0; s >>= 1) {
    if (tid < s) red[tid] += red[tid + s];
    __syncthreads();
  }
  const float inv = 1.0f / sqrtf(red[0]);
#pragma unroll
  for (int r = 0; r < 8; ++r) {
    const int i = tid + 256 * r;
    w1out[(size_t)h * IND + i] = val[r] * inv;
  }
}

// ---------------------------------------------------------------------------
// K5: w2_new[o,h] = (w2[o,h] + dw2T[h,o]) / ||row o||_2
// ---------------------------------------------------------------------------
__global__ __launch_bounds__(256) void k_w2(
    const float* __restrict__ w2, const float* __restrict__ heb,
    const float* __restrict__ corr2, const float* __restrict__ actsum,
    const float* __restrict__ outsum, float* __restrict__ w2out) {
  const int o = blockIdx.x * 256 + threadIdx.x;
  const float oso = outsum[o];
  const float4* heb4 = (const float4*)heb;

  float val[HID];
  float ss = 0.f;
#pragma unroll
  for (int h = 0; h < HID; ++h) {
    float4 c = heb4[(size_t)(HID * IND) + (size_t)h * OUTD + o];
    float v = w2[(size_t)o * HID + h] + 16384.0f * c.w +
              c.x * corr2[(size_t)h * OUTD + o] + c.y * actsum[h] + c.z * oso;
    val[h] = v;
    ss += v * v;
  }
  const float inv = 1.0f / sqrtf(ss);
#pragma unroll
  for (int h = 0; h < HID; ++h) w2out[(size_t)o * HID + h] = val[h] * inv;
}

// ---------------------------------------------------------------------------
extern "C" void kernel_launch(void* const* d_in, const int* in_sizes, int n_in,
                              void* d_out, int out_size, void* d_ws,
                              size_t ws_size, hipStream_t stream) {
  const float* x   = (const float*)d_in[0];   // [16384, 2048]
  const float* w1  = (const float*)d_in[1];   // [32, 2048]
  const float* w2  = (const float*)d_in[2];   // [512, 32]
  const float* heb = (const float*)d_in[3];   // [81920, 4]

  float* out = (float*)d_out;                 // [16384, 512]
  float* w1o = out + (size_t)BATCH * OUTD;    // [32, 2048]
  float* w2o = w1o + (size_t)HID * IND;       // [512, 32]

  float* ws = (float*)d_ws;                   // ws ~537 MB; layout ~105 MB
  unsigned short* actH = (unsigned short*)ws;                      // 262144 f
  unsigned short* actL = actH + (size_t)BATCH * HID;               // 262144 f
  unsigned short* actT = actL + (size_t)BATCH * HID;               // 262144 f
  unsigned short* w1H  = actT + (size_t)BATCH * HID;               // 32768 f
  unsigned short* w1L  = w1H + (size_t)HID * IND;                  // 32768 f
  unsigned short* w2H  = w1L + (size_t)HID * IND;                  // 8192 f
  unsigned short* w2L  = w2H + (size_t)OUTD * HID;                 // 8192 f
  unsigned short* xH   = w2L + (size_t)OUTD * HID;                 // 16.8M f
  float* corr1T      = (float*)(xH + (size_t)BATCH * IND);         // 65536
  float* corr2       = corr1T + (size_t)IND * HID;                 // 16384
  float* xsum        = corr2 + (size_t)HID * OUTD;                 // 2048
  float* actsum      = xsum + IND;                                 // 32
  float* outsum      = actsum + HID;                               // 512
  float* corr1T_part = outsum + OUTD;                              // 64*65536
  float* xsum_part   = corr1T_part + (size_t)NC1 * IND * HID;      // 64*2048
  float* actsum_part = xsum_part + (size_t)NC1 * IND;              // 512*32
  float* corr2_part  = actsum_part + (size_t)NSA * HID;            // 128*16384
  float* outsum_part = corr2_part + (size_t)NC2 * HID * OUTD;      // 128*512

  k_cvtw <<<80, 256, 0, stream>>>(w1, w2, w1H, w1L, w2H, w2L);
  k_act  <<<512, 256, 0, stream>>>(x, w1H, w1L, xH, actH, actL, actT,
                                   actsum_part);
  k_corr1<<<1024, 512, 0, stream>>>(xH, actT, corr1T_part, xsum_part);
  k_red1 <<<256, 256, 0, stream>>>(corr1T_part, xsum_part, actsum_part,
                                   corr1T, xsum, actsum);
  k_fwd2m<<<512, 256, 0, stream>>>(actH, actL, actT, w2H, w2L, out,
                                   corr2_part, outsum_part);
  k_red2 <<<64, 256, 0, stream>>>(corr2_part, outsum_part, corr2, outsum);
  k_w1   <<<32, 256, 0, stream>>>(w1, heb, corr1T, xsum, actsum, w1o);
  k_w2   <<<2, 256, 0, stream>>>(w2, heb, corr2, actsum, outsum, w2o);
}

// Round 23
// 115.865 us; speedup vs baseline: 1.2144x; 1.2144x over previous
//
#include <hip/hip_runtime.h>
#include <math.h>

// Problem constants
constexpr int BATCH = 16384;
constexpr int IND   = 2048;   // INPUT
constexpr int HID   = 32;     // HIDDEN
constexpr int OUTD  = 512;    // OUTPUT

constexpr int NC1 = 64;       // corr1/xsum partial slices (b-chunks of 256)
constexpr int NSA = 64;       // actsum partial slices (k_actc blocks)
constexpr int NC2 = 128;      // corr2/outsum partial slices (b-chunks of 128)

constexpr int SA   = 136;     // ushort row stride, k_act tiles
constexpr int SXT  = 72;      // ushort row stride, k_corr1 xT tile (64 b)
constexpr int SATW = 136;     // ushort row stride, k_fwd2m actT tile (128 b)
constexpr int SAT2 = 264;     // ushort row stride, k_corr1 actT tile (256 b)

typedef __attribute__((ext_vector_type(8))) short bf16x8;
typedef __attribute__((ext_vector_type(4))) float f32x4;

__device__ __forceinline__ unsigned short f2bf(float f) {
  unsigned u = __float_as_uint(f);
  u += 0x7FFFu + ((u >> 16) & 1u);          // round-to-nearest-even
  return (unsigned short)(u >> 16);
}
__device__ __forceinline__ float bf2f(unsigned short h) {
  return __uint_as_float(((unsigned)h) << 16);
}
__device__ __forceinline__ void split2(float f, unsigned short& hi,
                                       unsigned short& lo) {
  hi = f2bf(f);
  lo = f2bf(f - bf2f(hi));
}
__device__ __forceinline__ int swzA(int row, int col) {
  return row * SA + (col ^ (((row >> 3) & 7) * 8));
}

// ---------------------------------------------------------------------------
// K0: pre-split w1/w2 to hi/lo bf16 once (r19-verified).
// ---------------------------------------------------------------------------
__global__ __launch_bounds__(256) void k_cvtw(
    const float* __restrict__ w1, const float* __restrict__ w2,
    unsigned short* __restrict__ w1H, unsigned short* __restrict__ w1L,
    unsigned short* __restrict__ w2H, unsigned short* __restrict__ w2L) {
  const int bid = blockIdx.x;
  if (bid < 64) {
    const int g = bid * 256 + threadIdx.x;          // < 16384
    float4 v = ((const float4*)w1)[g];
    ushort4 h, l;
    split2(v.x, h.x, l.x); split2(v.y, h.y, l.y);
    split2(v.z, h.z, l.z); split2(v.w, h.w, l.w);
    ((ushort4*)w1H)[g] = h;
    ((ushort4*)w1L)[g] = l;
  } else {
    const int g = (bid - 64) * 256 + threadIdx.x;   // < 4096
    float4 v = ((const float4*)w2)[g];
    ushort4 h, l;
    split2(v.x, h.x, l.x); split2(v.y, h.y, l.y);
    split2(v.z, h.z, l.z); split2(v.w, h.w, l.w);
    ((ushort4*)w2H)[g] = h;
    ((ushort4*)w2L)[g] = l;
  }
}

// ---------------------------------------------------------------------------
// K1a: act partials = x @ w1T, split-bf16 MFMA; also emits xH bf16 [b][k]
// (r20-verified). grid = 1024 = (bt x 32 rows) x kq; (256,4).
// r22 lesson: fusing to full-K/grid-512 regressed +24us — this kernel
// family needs 4 blk/CU; keep the K-split x2 + separate combine.
// ---------------------------------------------------------------------------
__global__ __launch_bounds__(256, 4) void k_act(
    const float* __restrict__ x, const unsigned short* __restrict__ w1H,
    const unsigned short* __restrict__ w1L, float* __restrict__ act_part,
    unsigned short* __restrict__ xH) {
  const int tid = threadIdx.x;
  const int kq = blockIdx.x & 1;
  const int bt = blockIdx.x >> 1;          // 0..511
  const int b0 = bt * 32;
  const int kbase = kq * 1024;
  const int lane = tid & 63;
  const int wv = tid >> 6;                 // 0..3
  const int arow = lane & 15;
  const int m4 = lane >> 4;                // 0..3
  const int ksub = m4 * 8;
  const int rt = wv & 1;
  const int ht = wv >> 1;

  __shared__ __align__(16) unsigned short XH[32 * SA];
  __shared__ __align__(16) unsigned short XL[32 * SA];
  __shared__ __align__(16) unsigned short WH[32 * SA];
  __shared__ __align__(16) unsigned short WL[32 * SA];

  const int rp = tid >> 4;
  const int kg = (tid & 15) * 8;

  float4 px0a, px0b, px1a, px1b;
  bf16x8 pwh0, pwl0, pwh1, pwl1;

#define LOADA(K0)                                                          \
  {                                                                        \
    const float* xr0 = x + (size_t)(b0 + 2 * rp) * IND + kbase + (K0) + kg;\
    const float* xr1 = xr0 + IND;                                          \
    px0a = *(const float4*)(xr0);                                          \
    px0b = *(const float4*)(xr0 + 4);                                      \
    px1a = *(const float4*)(xr1);                                          \
    px1b = *(const float4*)(xr1 + 4);                                      \
    const size_t wo = (size_t)(2 * rp) * IND + kbase + (K0) + kg;          \
    pwh0 = *(const bf16x8*)(&w1H[wo]);                                     \
    pwl0 = *(const bf16x8*)(&w1L[wo]);                                     \
    pwh1 = *(const bf16x8*)(&w1H[wo + IND]);                               \
    pwl1 = *(const bf16x8*)(&w1L[wo + IND]);                               \
  }

#define PUTX2(ROW, COL, V, GK)                                       \
  {                                                                  \
    ushort4 h_, l_;                                                  \
    split2((V).x, h_.x, l_.x); split2((V).y, h_.y, l_.y);            \
    split2((V).z, h_.z, l_.z); split2((V).w, h_.w, l_.w);            \
    *(ushort4*)(&XH[swzA((ROW), (COL))]) = h_;                       \
    *(ushort4*)(&XL[swzA((ROW), (COL))]) = l_;                       \
    *(ushort4*)(&xH[(size_t)(b0 + (ROW)) * IND + (GK) + (COL)]) = h_;\
  }

#define STOREA(GK)                                                   \
  {                                                                  \
    PUTX2(2 * rp, kg, px0a, GK);                                     \
    PUTX2(2 * rp, kg + 4, px0b, GK);                                 \
    PUTX2(2 * rp + 1, kg, px1a, GK);                                 \
    PUTX2(2 * rp + 1, kg + 4, px1b, GK);                             \
    *(bf16x8*)(&WH[swzA(2 * rp, kg)]) = pwh0;                        \
    *(bf16x8*)(&WL[swzA(2 * rp, kg)]) = pwl0;                        \
    *(bf16x8*)(&WH[swzA(2 * rp + 1, kg)]) = pwh1;                    \
    *(bf16x8*)(&WL[swzA(2 * rp + 1, kg)]) = pwl1;                    \
  }

  f32x4 accA = {0.f, 0.f, 0.f, 0.f};
  LOADA(0);

  for (int kc = 0; kc < 8; ++kc) {
    __syncthreads();
    STOREA(kbase + kc * 128);
    __syncthreads();
    if (kc < 7) LOADA((kc + 1) * 128);
    const int xrow = rt * 16 + arow;
    const int wrow = ht * 16 + arow;
#pragma unroll
    for (int ks = 0; ks < 4; ++ks) {
      const int kk = ks * 32 + ksub;
      bf16x8 ah = *(const bf16x8*)(&XH[swzA(xrow, kk)]);
      bf16x8 al = *(const bf16x8*)(&XL[swzA(xrow, kk)]);
      bf16x8 bh = *(const bf16x8*)(&WH[swzA(wrow, kk)]);
      bf16x8 bl_ = *(const bf16x8*)(&WL[swzA(wrow, kk)]);
      accA = __builtin_amdgcn_mfma_f32_16x16x32_bf16(ah, bh, accA, 0, 0, 0);
      accA = __builtin_amdgcn_mfma_f32_16x16x32_bf16(ah, bl_, accA, 0, 0, 0);
      accA = __builtin_amdgcn_mfma_f32_16x16x32_bf16(al, bh, accA, 0, 0, 0);
    }
  }

  const int bl = rt * 16 + (m4 << 2);
  const int h = ht * 16 + arow;
  float* p = act_part + (size_t)kq * (BATCH * HID);
#pragma unroll
  for (int r = 0; r < 4; ++r)
    p[(size_t)(b0 + bl + r) * HID + h] = accA[r];
}

// ---------------------------------------------------------------------------
// K1b: combine K-half partials -> relu -> actH/actL [b][h] + actT [h][b] +
// actsum partials (r19-verbatim). grid = 64 x 256.
// ---------------------------------------------------------------------------
__global__ __launch_bounds__(256) void k_actc(
    const float* __restrict__ act_part,
    unsigned short* __restrict__ actH, unsigned short* __restrict__ actL,
    unsigned short* __restrict__ actT, float* __restrict__ actsum_part) {
  const int tid = threadIdx.x;
  const int blk = blockIdx.x;              // 0..63
  const int b0 = blk * 256;

  __shared__ unsigned short asT[32][264];
  __shared__ float red[256][4];

  const float4* p0 = (const float4*)act_part;
  const float4* p1 = p0 + (size_t)BATCH * HID / 4;

  const int hq = tid & 7;
  float4 s{0.f, 0.f, 0.f, 0.f};
#pragma unroll
  for (int r = 0; r < 8; ++r) {
    const int e4 = r * 256 + tid;
    const int b = e4 >> 3;
    const size_t g = (size_t)(b0 + b) * 8 + hq;
    float4 a = p0[g];
    float4 c = p1[g];
    a.x = fmaxf(a.x + c.x, 0.f);  a.y = fmaxf(a.y + c.y, 0.f);
    a.z = fmaxf(a.z + c.z, 0.f);  a.w = fmaxf(a.w + c.w, 0.f);
    ushort4 hh, ll;
    split2(a.x, hh.x, ll.x); split2(a.y, hh.y, ll.y);
    split2(a.z, hh.z, ll.z); split2(a.w, hh.w, ll.w);
    *(ushort4*)(&actH[g * 4]) = hh;
    *(ushort4*)(&actL[g * 4]) = ll;
    asT[hq * 4 + 0][b] = hh.x;
    asT[hq * 4 + 1][b] = hh.y;
    asT[hq * 4 + 2][b] = hh.z;
    asT[hq * 4 + 3][b] = hh.w;
    s.x += a.x; s.y += a.y; s.z += a.z; s.w += a.w;
  }
  red[tid][0] = s.x; red[tid][1] = s.y;
  red[tid][2] = s.z; red[tid][3] = s.w;
  __syncthreads();

#pragma unroll
  for (int r = 0; r < 4; ++r) {
    const int slot = r * 256 + tid;
    const int hrow = slot >> 5;
    const int bseg = (slot & 31) * 8;
    bf16x8 v = *(const bf16x8*)(&asT[hrow][bseg]);
    *(bf16x8*)(&actT[(size_t)hrow * BATCH + b0 + bseg]) = v;
  }
  if (tid < 32) {
    const int q = tid >> 2, j = tid & 3;
    float t = 0.f;
#pragma unroll
    for (int sx = 0; sx < 32; ++sx) t += red[q + 8 * sx][j];
    actsum_part[blk * HID + tid] = t;
  }
}

// ---------------------------------------------------------------------------
// K1c: corr1T_part = x^T @ act (+ xsum via ones tile), reading xH bf16.
// 256-b chunks: FOUR 64-b halves accumulated in C-regs -> NC1=64
// (r21-verified, -10.8us). grid = 1024 = (bc 0..63 x 256 b) x (iq 0..15
// x 128 i); 512 thr, (512,3).
// ---------------------------------------------------------------------------
__global__ __launch_bounds__(512, 3) void k_corr1(
    const unsigned short* __restrict__ xH,
    const unsigned short* __restrict__ actT,
    float* __restrict__ corr1T_part, float* __restrict__ xsum_part) {
  const int tid = threadIdx.x;
  const int bc = blockIdx.x >> 4;          // 0..63
  const int iq = blockIdx.x & 15;          // 0..15
  const int b0 = bc * 256;
  const int ibase = iq * 128;
  const int lane = tid & 63;
  const int wv = tid >> 6;                 // 0..7
  const int arow = lane & 15;
  const int m4 = lane >> 4;
  const int ksub = m4 * 8;
  const int it = wv * 16;                  // wave's i-tile base (0..112)

  __shared__ __align__(16) unsigned short XT[128 * SXT];   // [128 i][64 b]
  __shared__ __align__(16) unsigned short AT[48 * SAT2];   // [48][256 b]

  for (int e = tid; e < 16 * SAT2; e += 512)
    AT[32 * SAT2 + e] = (unsigned short)0x3F80;
  {
    const int hrow = tid >> 4;             // 0..31
    const int sg = (tid & 15) * 16;        // 0..240
    const int sw = ((hrow >> 3) & 7) * 8;
#pragma unroll
    for (int j = 0; j < 2; ++j) {
      const int boff = sg + 8 * j;
      bf16x8 v = *(const bf16x8*)(&actT[(size_t)hrow * BATCH + b0 + boff]);
      *(bf16x8*)(&AT[hrow * SAT2 + (boff ^ sw)]) = v;
    }
  }

  const int ig = tid & 15;                 // i-group (8 i)
  const int bq = tid >> 4;                 // 0..31 -> half-local rows 2bq,2bq+1

  bf16x8 xa, ya;

#define LOADC(HF)                                                           \
  {                                                                         \
    const int icol = ibase + ig * 8;                                        \
    const unsigned short* r0 =                                              \
        xH + (size_t)(b0 + 64 * (HF) + 2 * bq) * IND + icol;                \
    xa = *(const bf16x8*)(r0);                                              \
    ya = *(const bf16x8*)(r0 + IND);                                        \
  }

#define STC                                                                 \
  {                                                                         \
    const int qb = (2 * bq) ^ ((ig & 7) * 8);                               \
    unsigned short* basew = &XT[(size_t)(ig * 8) * SXT + qb];               \
    ushort2 p;                                                              \
    p.x = (unsigned short)xa[0]; p.y = (unsigned short)ya[0];               \
    *(ushort2*)(basew + 0 * SXT) = p;                                       \
    p.x = (unsigned short)xa[1]; p.y = (unsigned short)ya[1];               \
    *(ushort2*)(basew + 1 * SXT) = p;                                       \
    p.x = (unsigned short)xa[2]; p.y = (unsigned short)ya[2];               \
    *(ushort2*)(basew + 2 * SXT) = p;                                       \
    p.x = (unsigned short)xa[3]; p.y = (unsigned short)ya[3];               \
    *(ushort2*)(basew + 3 * SXT) = p;                                       \
    p.x = (unsigned short)xa[4]; p.y = (unsigned short)ya[4];               \
    *(ushort2*)(basew + 4 * SXT) = p;                                       \
    p.x = (unsigned short)xa[5]; p.y = (unsigned short)ya[5];               \
    *(ushort2*)(basew + 5 * SXT) = p;                                       \
    p.x = (unsigned short)xa[6]; p.y = (unsigned short)ya[6];               \
    *(ushort2*)(basew + 6 * SXT) = p;                                       \
    p.x = (unsigned short)xa[7]; p.y = (unsigned short)ya[7];               \
    *(ushort2*)(basew + 7 * SXT) = p;                                       \
  }

  const int swzr = (((it + arow) >> 3) & 7) * 8;
  const int swze0 = ((arow >> 3) & 7) * 8;
  const int swze1 = (((16 + arow) >> 3) & 7) * 8;

  f32x4 c00 = {0.f, 0.f, 0.f, 0.f};
  f32x4 c01 = {0.f, 0.f, 0.f, 0.f};
  f32x4 c02 = {0.f, 0.f, 0.f, 0.f};

  LOADC(0);
#pragma unroll
  for (int hf = 0; hf < 4; ++hf) {
    __syncthreads();
    STC;
    __syncthreads();
    if (hf < 3) LOADC(hf + 1);
#pragma unroll
    for (int bs = 0; bs < 2; ++bs) {
      const int bb = bs * 32 + ksub;
      const int bb2 = 64 * hf + bb;
      bf16x8 a = *(const bf16x8*)(&XT[(it + arow) * SXT + (bb ^ swzr)]);
      bf16x8 e0 = *(const bf16x8*)(&AT[arow * SAT2 + (bb2 ^ swze0)]);
      bf16x8 e1 = *(const bf16x8*)(&AT[(16 + arow) * SAT2 + (bb2 ^ swze1)]);
      bf16x8 e2 = *(const bf16x8*)(&AT[(32 + arow) * SAT2 + bb2]);
      c00 = __builtin_amdgcn_mfma_f32_16x16x32_bf16(a, e0, c00, 0, 0, 0);
      c01 = __builtin_amdgcn_mfma_f32_16x16x32_bf16(a, e1, c01, 0, 0, 0);
      c02 = __builtin_amdgcn_mfma_f32_16x16x32_bf16(a, e2, c02, 0, 0, 0);
    }
  }

  float* basep = corr1T_part + (size_t)bc * (IND * HID);
  const int gi = ibase + it + (m4 << 2);
  *(f32x4*)(basep + (size_t)arow * IND + gi) = c00;
  *(f32x4*)(basep + (size_t)(16 + arow) * IND + gi) = c01;
  if (arow == 0)
    *(f32x4*)(xsum_part + (size_t)bc * IND + gi) = c02;
}

// ---------------------------------------------------------------------------
// K1d: deterministic reduce (corr1T/xsum: 64 slices, actsum: 64).
// ---------------------------------------------------------------------------
__global__ __launch_bounds__(256) void k_red1(
    const float* __restrict__ c1p, const float* __restrict__ xsp,
    const float* __restrict__ asp,
    float* __restrict__ corr1T, float* __restrict__ xsum,
    float* __restrict__ actsum) {
  const int e = blockIdx.x * 256 + threadIdx.x;
  float s = 0.f;
#pragma unroll 8
  for (int c = 0; c < NC1; ++c) s += c1p[(size_t)c * (IND * HID) + e];
  corr1T[e] = s;
  if (e < IND) {
    float t = 0.f;
#pragma unroll 8
    for (int c = 0; c < NC1; ++c) t += xsp[(size_t)c * IND + e];
    xsum[e] = t;
  }
  if (e < HID) {
    float t = 0.f;
#pragma unroll 8
    for (int c = 0; c < NSA; ++c) t += asp[(size_t)c * HID + e];
    actsum[e] = t;
  }
}

// ---------------------------------------------------------------------------
// K3: layer-2 MFMA, 128-b blocks, C-reg accumulation across halves
// (r20-verified). grid = 512 = (bc 0..127) x (og 0..3); 256 thr.
// ---------------------------------------------------------------------------
__global__ __launch_bounds__(256, 2) void k_fwd2m(
    const unsigned short* __restrict__ actH,
    const unsigned short* __restrict__ actL,
    const unsigned short* __restrict__ actT,
    const unsigned short* __restrict__ w2H,
    const unsigned short* __restrict__ w2L,
    float* __restrict__ out, float* __restrict__ corr2_part,
    float* __restrict__ outsum_part) {
  const int tid = threadIdx.x;
  const int bc = blockIdx.x >> 2;          // 0..127
  const int og = blockIdx.x & 3;           // 0..3
  const int b0 = bc * 128;
  const int obase = og * 128;
  const int lane = tid & 63;
  const int wv = tid >> 6;                 // 0..3
  const int arow = lane & 15;
  const int m4 = lane >> 4;
  const int ksub = m4 * 8;

  __shared__ __align__(16) unsigned short W2Hs[128 * 40];
  __shared__ __align__(16) unsigned short W2Ls[128 * 40];
  __shared__ __align__(16) unsigned short AH[64 * 40];
  __shared__ __align__(16) unsigned short AL[64 * 40];
  __shared__ __align__(16) unsigned short AT[48 * SATW];
  __shared__ __align__(16) unsigned short OT[128 * 72];

  {
    const int r2 = tid >> 1, hh = (tid & 1) * 16;
    const size_t wo = (size_t)(obase + r2) * HID + hh;
    *(bf16x8*)(&W2Hs[r2 * 40 + hh]) = *(const bf16x8*)(&w2H[wo]);
    *(bf16x8*)(&W2Hs[r2 * 40 + hh + 8]) = *(const bf16x8*)(&w2H[wo + 8]);
    *(bf16x8*)(&W2Ls[r2 * 40 + hh]) = *(const bf16x8*)(&w2L[wo]);
    *(bf16x8*)(&W2Ls[r2 * 40 + hh + 8]) = *(const bf16x8*)(&w2L[wo + 8]);
  }
  {
    const int h = tid >> 3, seg16 = (tid & 7) * 16;
#pragma unroll
    for (int j = 0; j < 2; ++j) {
      const int seg = seg16 + 8 * j;
      *(bf16x8*)(&AT[h * SATW + seg]) =
          *(const bf16x8*)(&actT[(size_t)h * BATCH + b0 + seg]);
    }
  }
  for (int e = tid; e < 16 * SATW; e += 256)
    AT[32 * SATW + e] = (unsigned short)0x3F80;

  f32x4 c0a = {0.f,0.f,0.f,0.f}, c1a = {0.f,0.f,0.f,0.f}, c2a = {0.f,0.f,0.f,0.f};
  f32x4 c0b = {0.f,0.f,0.f,0.f}, c1b = {0.f,0.f,0.f,0.f}, c2b = {0.f,0.f,0.f,0.f};

  for (int hf = 0; hf < 2; ++hf) {
    __syncthreads();
    {
      const int b = tid >> 2, q = (tid & 3) * 8;
      *(bf16x8*)(&AH[b * 40 + q]) =
          *(const bf16x8*)(&actH[(size_t)(b0 + 64 * hf + b) * HID + q]);
      *(bf16x8*)(&AL[b * 40 + q]) =
          *(const bf16x8*)(&actL[(size_t)(b0 + 64 * hf + b) * HID + q]);
    }
    __syncthreads();

    const int bt = wv;
    bf16x8 fah = *(const bf16x8*)(&AH[(bt * 16 + arow) * 40 + ksub]);
    bf16x8 fal = *(const bf16x8*)(&AL[(bt * 16 + arow) * 40 + ksub]);
#pragma unroll
    for (int ot = 0; ot < 8; ++ot) {
      bf16x8 wbh = *(const bf16x8*)(&W2Hs[(ot * 16 + arow) * 40 + ksub]);
      bf16x8 wbl = *(const bf16x8*)(&W2Ls[(ot * 16 + arow) * 40 + ksub]);
      f32x4 z = {0.f, 0.f, 0.f, 0.f};
      z = __builtin_amdgcn_mfma_f32_16x16x32_bf16(fah, wbh, z, 0, 0, 0);
      z = __builtin_amdgcn_mfma_f32_16x16x32_bf16(fah, wbl, z, 0, 0, 0);
      z = __builtin_amdgcn_mfma_f32_16x16x32_bf16(fal, wbh, z, 0, 0, 0);
      ushort4 po;
      {
        float ov0 = 1.0f / (1.0f + __expf(-z[0])) - 0.4f;
        float ov1 = 1.0f / (1.0f + __expf(-z[1])) - 0.4f;
        float ov2 = 1.0f / (1.0f + __expf(-z[2])) - 0.4f;
        float ov3 = 1.0f / (1.0f + __expf(-z[3])) - 0.4f;
        const size_t ob = (size_t)(b0 + 64 * hf + bt * 16 + m4 * 4) * OUTD +
                          obase + ot * 16 + arow;
        out[ob + 0 * OUTD] = ov0;
        out[ob + 1 * OUTD] = ov1;
        out[ob + 2 * OUTD] = ov2;
        out[ob + 3 * OUTD] = ov3;
        po.x = f2bf(ov0); po.y = f2bf(ov1); po.z = f2bf(ov2); po.w = f2bf(ov3);
      }
      *(ushort4*)(&OT[(ot * 16 + arow) * 72 + bt * 16 + m4 * 4]) = po;
    }
    __syncthreads();

    {
      const int ot = wv * 2;
#pragma unroll
      for (int ks = 0; ks < 2; ++ks) {
        const int bb = ks * 32 + ksub;
        const int bb2 = 64 * hf + bb;
        bf16x8 bo = *(const bf16x8*)(&OT[(ot * 16 + arow) * 72 + bb]);
        bf16x8 a0 = *(const bf16x8*)(&AT[arow * SATW + bb2]);
        bf16x8 a1 = *(const bf16x8*)(&AT[(16 + arow) * SATW + bb2]);
        bf16x8 a2 = *(const bf16x8*)(&AT[(32 + arow) * SATW + bb2]);
        c0a = __builtin_amdgcn_mfma_f32_16x16x32_bf16(a0, bo, c0a, 0, 0, 0);
        c1a = __builtin_amdgcn_mfma_f32_16x16x32_bf16(a1, bo, c1a, 0, 0, 0);
        c2a = __builtin_amdgcn_mfma_f32_16x16x32_bf16(a2, bo, c2a, 0, 0, 0);
      }
    }
    {
      const int ot = wv * 2 + 1;
#pragma unroll
      for (int ks = 0; ks < 2; ++ks) {
        const int bb = ks * 32 + ksub;
        const int bb2 = 64 * hf + bb;
        bf16x8 bo = *(const bf16x8*)(&OT[(ot * 16 + arow) * 72 + bb]);
        bf16x8 a0 = *(const bf16x8*)(&AT[arow * SATW + bb2]);
        bf16x8 a1 = *(const bf16x8*)(&AT[(16 + arow) * SATW + bb2]);
        bf16x8 a2 = *(const bf16x8*)(&AT[(32 + arow) * SATW + bb2]);
        c0b = __builtin_amdgcn_mfma_f32_16x16x32_bf16(a0, bo, c0b, 0, 0, 0);
        c1b = __builtin_amdgcn_mfma_f32_16x16x32_bf16(a1, bo, c1b, 0, 0, 0);
        c2b = __builtin_amdgcn_mfma_f32_16x16x32_bf16(a2, bo, c2b, 0, 0, 0);
      }
    }
  }

  {
    const int ot0 = wv * 2, ot1 = wv * 2 + 1;
    float* cp0 = corr2_part + (size_t)bc * (HID * OUTD) + obase + ot0 * 16 + arow;
    float* cp1 = corr2_part + (size_t)bc * (HID * OUTD) + obase + ot1 * 16 + arow;
#pragma unroll
    for (int r = 0; r < 4; ++r) {
      cp0[(size_t)(m4 * 4 + r) * OUTD] = c0a[r];
      cp0[(size_t)(16 + m4 * 4 + r) * OUTD] = c1a[r];
      cp1[(size_t)(m4 * 4 + r) * OUTD] = c0b[r];
      cp1[(size_t)(16 + m4 * 4 + r) * OUTD] = c1b[r];
    }
    if (m4 == 0) {
      outsum_part[(size_t)bc * OUTD + obase + ot0 * 16 + arow] = c2a[0];
      outsum_part[(size_t)bc * OUTD + obase + ot1 * 16 + arow] = c2b[0];
    }
  }
}

// ---------------------------------------------------------------------------
// K3b: deterministic reduce of corr2/outsum partials (128 slices).
// ---------------------------------------------------------------------------
__global__ __launch_bounds__(256) void k_red2(
    const float* __restrict__ corr2_part, const float* __restrict__ outsum_part,
    float* __restrict__ corr2, float* __restrict__ outsum) {
  const int e = blockIdx.x * 256 + threadIdx.x;
  float s = 0.f;
#pragma unroll 8
  for (int c = 0; c < NC2; ++c) s += corr2_part[(size_t)c * (HID * OUTD) + e];
  corr2[e] = s;
  if (e < OUTD) {
    float t = 0.f;
#pragma unroll 8
    for (int c = 0; c < NC2; ++c) t += outsum_part[(size_t)c * OUTD + e];
    outsum[e] = t;
  }
}

// ---------------------------------------------------------------------------
// K4: w1_new[h,i] = (w1[h,i] + dw1T[i,h]) / ||row h||_2 ; corr1T[h][i].
// ---------------------------------------------------------------------------
__global__ __launch_bounds__(256) void k_w1(
    const float* __restrict__ w1, const float* __restrict__ heb,
    const float* __restrict__ corr1T, const float* __restrict__ xsum,
    const float* __restrict__ actsum, float* __restrict__ w1out) {
  const int h = blockIdx.x;
  const int tid = threadIdx.x;
  const float ash = actsum[h];
  const float4* heb4 = (const float4*)heb;

  float val[8];
  float ss = 0.f;
#pragma unroll
  for (int r = 0; r < 8; ++r) {
    const int i = tid + 256 * r;
    float4 c = heb4[(size_t)i * HID + h];
    float v = w1[(size_t)h * IND + i] + 16384.0f * c.w +
              c.x * corr1T[(size_t)h * IND + i] + c.y * xsum[i] + c.z * ash;
    val[r] = v;
    ss += v * v;
  }

  __shared__ float red[256];
  red[tid] = ss;
  __syncthreads();
  for (int s = 128; s > 0; s >>= 1) {
    if (tid < s) red[tid] += red[tid + s];
    __syncthreads();
  }
  const float inv = 1.0f / sqrtf(red[0]);
#pragma unroll
  for (int r = 0; r < 8; ++r) {
    const int i = tid + 256 * r;
    w1out[(size_t)h * IND + i] = val[r] * inv;
  }
}

// ---------------------------------------------------------------------------
// K5: w2_new[o,h] = (w2[o,h] + dw2T[h,o]) / ||row o||_2
// ---------------------------------------------------------------------------
__global__ __launch_bounds__(256) void k_w2(
    const float* __restrict__ w2, const float* __restrict__ heb,
    const float* __restrict__ corr2, const float* __restrict__ actsum,
    const float* __restrict__ outsum, float* __restrict__ w2out) {
  const int o = blockIdx.x * 256 + threadIdx.x;
  const float oso = outsum[o];
  const float4* heb4 = (const float4*)heb;

  float val[HID];
  float ss = 0.f;
#pragma unroll
  for (int h = 0; h < HID; ++h) {
    float4 c = heb4[(size_t)(HID * IND) + (size_t)h * OUTD + o];
    float v = w2[(size_t)o * HID + h] + 16384.0f * c.w +
              c.x * corr2[(size_t)h * OUTD + o] + c.y * actsum[h] + c.z * oso;
    val[h] = v;
    ss += v * v;
  }
  const float inv = 1.0f / sqrtf(ss);
#pragma unroll
  for (int h = 0; h < HID; ++h) w2out[(size_t)o * HID + h] = val[h] * inv;
}

// ---------------------------------------------------------------------------
extern "C" void kernel_launch(void* const* d_in, const int* in_sizes, int n_in,
                              void* d_out, int out_size, void* d_ws,
                              size_t ws_size, hipStream_t stream) {
  const float* x   = (const float*)d_in[0];   // [16384, 2048]
  const float* w1  = (const float*)d_in[1];   // [32, 2048]
  const float* w2  = (const float*)d_in[2];   // [512, 32]
  const float* heb = (const float*)d_in[3];   // [81920, 4]

  float* out = (float*)d_out;                 // [16384, 512]
  float* w1o = out + (size_t)BATCH * OUTD;    // [32, 2048]
  float* w2o = w1o + (size_t)HID * IND;       // [512, 32]

  float* ws = (float*)d_ws;                   // ws ~537 MB; layout ~110 MB
  unsigned short* actH = (unsigned short*)ws;                      // 262144 f
  unsigned short* actL = actH + (size_t)BATCH * HID;               // 262144 f
  unsigned short* actT = actL + (size_t)BATCH * HID;               // 262144 f
  unsigned short* w1H  = actT + (size_t)BATCH * HID;               // 32768 f
  unsigned short* w1L  = w1H + (size_t)HID * IND;                  // 32768 f
  unsigned short* w2H  = w1L + (size_t)HID * IND;                  // 8192 f
  unsigned short* w2L  = w2H + (size_t)OUTD * HID;                 // 8192 f
  unsigned short* xH   = w2L + (size_t)OUTD * HID;                 // 16.8M f
  float* corr1T      = (float*)(xH + (size_t)BATCH * IND);         // 65536
  float* corr2       = corr1T + (size_t)IND * HID;                 // 16384
  float* xsum        = corr2 + (size_t)HID * OUTD;                 // 2048
  float* actsum      = xsum + IND;                                 // 32
  float* outsum      = actsum + HID;                               // 512
  float* act_part    = outsum + OUTD;                              // 2*524288
  float* corr1T_part = act_part + (size_t)2 * BATCH * HID;         // 64*65536
  float* xsum_part   = corr1T_part + (size_t)NC1 * IND * HID;      // 64*2048
  float* actsum_part = xsum_part + (size_t)NC1 * IND;              // 64*32
  float* corr2_part  = actsum_part + (size_t)NSA * HID;            // 128*16384
  float* outsum_part = corr2_part + (size_t)NC2 * HID * OUTD;      // 128*512

  k_cvtw <<<80, 256, 0, stream>>>(w1, w2, w1H, w1L, w2H, w2L);
  k_act  <<<1024, 256, 0, stream>>>(x, w1H, w1L, act_part, xH);
  k_actc <<<64, 256, 0, stream>>>(act_part, actH, actL, actT, actsum_part);
  k_corr1<<<1024, 512, 0, stream>>>(xH, actT, corr1T_part, xsum_part);
  k_red1 <<<256, 256, 0, stream>>>(corr1T_part, xsum_part, actsum_part,
                                   corr1T, xsum, actsum);
  k_fwd2m<<<512, 256, 0, stream>>>(actH, actL, actT, w2H, w2L, out,
                                   corr2_part, outsum_part);
  k_red2 <<<64, 256, 0, stream>>>(corr2_part, outsum_part, corr2, outsum);
  k_w1   <<<32, 256, 0, stream>>>(w1, heb, corr1T, xsum, actsum, w1o);
  k_w2   <<<2, 256, 0, stream>>>(w2, heb, corr2, actsum, outsum, w2o);
}

// Round 24
// 106.732 us; speedup vs baseline: 1.3183x; 1.0856x over previous
//
#include <hip/hip_runtime.h>
#include <math.h>

// Problem constants
constexpr int BATCH = 16384;
constexpr int IND   = 2048;   // INPUT
constexpr int HID   = 32;     // HIDDEN
constexpr int OUTD  = 512;    // OUTPUT

constexpr int NC1 = 64;       // corr1/xsum partial slices (b-chunks of 256)
constexpr int NSA = 64;       // actsum partial slices (k_actc blocks)
constexpr int NC2 = 128;      // corr2/outsum partial slices (b-chunks of 128)

constexpr int SA   = 136;     // ushort row stride, k_act tiles
constexpr int SXT  = 72;      // ushort row stride, k_corr1 xT tile (64 b)
constexpr int SATW = 136;     // ushort row stride, k_fwd2m actT tile (128 b)
constexpr int SAT2 = 264;     // ushort row stride, k_corr1 actT tile (256 b)

typedef __attribute__((ext_vector_type(8))) short bf16x8;
typedef __attribute__((ext_vector_type(4))) float f32x4;

__device__ __forceinline__ unsigned short f2bf(float f) {
  unsigned u = __float_as_uint(f);
  u += 0x7FFFu + ((u >> 16) & 1u);          // round-to-nearest-even
  return (unsigned short)(u >> 16);
}
__device__ __forceinline__ float bf2f(unsigned short h) {
  return __uint_as_float(((unsigned)h) << 16);
}
__device__ __forceinline__ void split2(float f, unsigned short& hi,
                                       unsigned short& lo) {
  hi = f2bf(f);
  lo = f2bf(f - bf2f(hi));
}
__device__ __forceinline__ int swzA(int row, int col) {
  return row * SA + (col ^ (((row >> 3) & 7) * 8));
}

// ---------------------------------------------------------------------------
// K0: pre-split w1/w2 to hi/lo bf16 once (r19-verified).
// ---------------------------------------------------------------------------
__global__ __launch_bounds__(256) void k_cvtw(
    const float* __restrict__ w1, const float* __restrict__ w2,
    unsigned short* __restrict__ w1H, unsigned short* __restrict__ w1L,
    unsigned short* __restrict__ w2H, unsigned short* __restrict__ w2L) {
  const int bid = blockIdx.x;
  if (bid < 64) {
    const int g = bid * 256 + threadIdx.x;          // < 16384
    float4 v = ((const float4*)w1)[g];
    ushort4 h, l;
    split2(v.x, h.x, l.x); split2(v.y, h.y, l.y);
    split2(v.z, h.z, l.z); split2(v.w, h.w, l.w);
    ((ushort4*)w1H)[g] = h;
    ((ushort4*)w1L)[g] = l;
  } else {
    const int g = (bid - 64) * 256 + threadIdx.x;   // < 4096
    float4 v = ((const float4*)w2)[g];
    ushort4 h, l;
    split2(v.x, h.x, l.x); split2(v.y, h.y, l.y);
    split2(v.z, h.z, l.z); split2(v.w, h.w, l.w);
    ((ushort4*)w2H)[g] = h;
    ((ushort4*)w2L)[g] = l;
  }
}

// ---------------------------------------------------------------------------
// K1a: act partials = x @ w1T, split-bf16 MFMA; also emits xH bf16 [b][k]
// (r20-verified). grid = 1024 = (bt x 32 rows) x kq; (256,4).
// ---------------------------------------------------------------------------
__global__ __launch_bounds__(256, 4) void k_act(
    const float* __restrict__ x, const unsigned short* __restrict__ w1H,
    const unsigned short* __restrict__ w1L, float* __restrict__ act_part,
    unsigned short* __restrict__ xH) {
  const int tid = threadIdx.x;
  const int kq = blockIdx.x & 1;
  const int bt = blockIdx.x >> 1;          // 0..511
  const int b0 = bt * 32;
  const int kbase = kq * 1024;
  const int lane = tid & 63;
  const int wv = tid >> 6;                 // 0..3
  const int arow = lane & 15;
  const int m4 = lane >> 4;                // 0..3
  const int ksub = m4 * 8;
  const int rt = wv & 1;
  const int ht = wv >> 1;

  __shared__ __align__(16) unsigned short XH[32 * SA];
  __shared__ __align__(16) unsigned short XL[32 * SA];
  __shared__ __align__(16) unsigned short WH[32 * SA];
  __shared__ __align__(16) unsigned short WL[32 * SA];

  const int rp = tid >> 4;
  const int kg = (tid & 15) * 8;

  float4 px0a, px0b, px1a, px1b;
  bf16x8 pwh0, pwl0, pwh1, pwl1;

#define LOADA(K0)                                                          \
  {                                                                        \
    const float* xr0 = x + (size_t)(b0 + 2 * rp) * IND + kbase + (K0) + kg;\
    const float* xr1 = xr0 + IND;                                          \
    px0a = *(const float4*)(xr0);                                          \
    px0b = *(const float4*)(xr0 + 4);                                      \
    px1a = *(const float4*)(xr1);                                          \
    px1b = *(const float4*)(xr1 + 4);                                      \
    const size_t wo = (size_t)(2 * rp) * IND + kbase + (K0) + kg;          \
    pwh0 = *(const bf16x8*)(&w1H[wo]);                                     \
    pwl0 = *(const bf16x8*)(&w1L[wo]);                                     \
    pwh1 = *(const bf16x8*)(&w1H[wo + IND]);                               \
    pwl1 = *(const bf16x8*)(&w1L[wo + IND]);                               \
  }

#define PUTX2(ROW, COL, V, GK)                                       \
  {                                                                  \
    ushort4 h_, l_;                                                  \
    split2((V).x, h_.x, l_.x); split2((V).y, h_.y, l_.y);            \
    split2((V).z, h_.z, l_.z); split2((V).w, h_.w, l_.w);            \
    *(ushort4*)(&XH[swzA((ROW), (COL))]) = h_;                       \
    *(ushort4*)(&XL[swzA((ROW), (COL))]) = l_;                       \
    *(ushort4*)(&xH[(size_t)(b0 + (ROW)) * IND + (GK) + (COL)]) = h_;\
  }

#define STOREA(GK)                                                   \
  {                                                                  \
    PUTX2(2 * rp, kg, px0a, GK);                                     \
    PUTX2(2 * rp, kg + 4, px0b, GK);                                 \
    PUTX2(2 * rp + 1, kg, px1a, GK);                                 \
    PUTX2(2 * rp + 1, kg + 4, px1b, GK);                             \
    *(bf16x8*)(&WH[swzA(2 * rp, kg)]) = pwh0;                        \
    *(bf16x8*)(&WL[swzA(2 * rp, kg)]) = pwl0;                        \
    *(bf16x8*)(&WH[swzA(2 * rp + 1, kg)]) = pwh1;                    \
    *(bf16x8*)(&WL[swzA(2 * rp + 1, kg)]) = pwl1;                    \
  }

  f32x4 accA = {0.f, 0.f, 0.f, 0.f};
  LOADA(0);

  for (int kc = 0; kc < 8; ++kc) {
    __syncthreads();
    STOREA(kbase + kc * 128);
    __syncthreads();
    if (kc < 7) LOADA((kc + 1) * 128);
    const int xrow = rt * 16 + arow;
    const int wrow = ht * 16 + arow;
#pragma unroll
    for (int ks = 0; ks < 4; ++ks) {
      const int kk = ks * 32 + ksub;
      bf16x8 ah = *(const bf16x8*)(&XH[swzA(xrow, kk)]);
      bf16x8 al = *(const bf16x8*)(&XL[swzA(xrow, kk)]);
      bf16x8 bh = *(const bf16x8*)(&WH[swzA(wrow, kk)]);
      bf16x8 bl_ = *(const bf16x8*)(&WL[swzA(wrow, kk)]);
      accA = __builtin_amdgcn_mfma_f32_16x16x32_bf16(ah, bh, accA, 0, 0, 0);
      accA = __builtin_amdgcn_mfma_f32_16x16x32_bf16(ah, bl_, accA, 0, 0, 0);
      accA = __builtin_amdgcn_mfma_f32_16x16x32_bf16(al, bh, accA, 0, 0, 0);
    }
  }

  const int bl = rt * 16 + (m4 << 2);
  const int h = ht * 16 + arow;
  float* p = act_part + (size_t)kq * (BATCH * HID);
#pragma unroll
  for (int r = 0; r < 4; ++r)
    p[(size_t)(b0 + bl + r) * HID + h] = accA[r];
}

// ---------------------------------------------------------------------------
// K1b: combine K-half partials -> relu -> actH/actL [b][h] + actT [h][b] +
// actsum partials (r19-verbatim). grid = 64 x 256.
// ---------------------------------------------------------------------------
__global__ __launch_bounds__(256) void k_actc(
    const float* __restrict__ act_part,
    unsigned short* __restrict__ actH, unsigned short* __restrict__ actL,
    unsigned short* __restrict__ actT, float* __restrict__ actsum_part) {
  const int tid = threadIdx.x;
  const int blk = blockIdx.x;              // 0..63
  const int b0 = blk * 256;

  __shared__ unsigned short asT[32][264];
  __shared__ float red[256][4];

  const float4* p0 = (const float4*)act_part;
  const float4* p1 = p0 + (size_t)BATCH * HID / 4;

  const int hq = tid & 7;
  float4 s{0.f, 0.f, 0.f, 0.f};
#pragma unroll
  for (int r = 0; r < 8; ++r) {
    const int e4 = r * 256 + tid;
    const int b = e4 >> 3;
    const size_t g = (size_t)(b0 + b) * 8 + hq;
    float4 a = p0[g];
    float4 c = p1[g];
    a.x = fmaxf(a.x + c.x, 0.f);  a.y = fmaxf(a.y + c.y, 0.f);
    a.z = fmaxf(a.z + c.z, 0.f);  a.w = fmaxf(a.w + c.w, 0.f);
    ushort4 hh, ll;
    split2(a.x, hh.x, ll.x); split2(a.y, hh.y, ll.y);
    split2(a.z, hh.z, ll.z); split2(a.w, hh.w, ll.w);
    *(ushort4*)(&actH[g * 4]) = hh;
    *(ushort4*)(&actL[g * 4]) = ll;
    asT[hq * 4 + 0][b] = hh.x;
    asT[hq * 4 + 1][b] = hh.y;
    asT[hq * 4 + 2][b] = hh.z;
    asT[hq * 4 + 3][b] = hh.w;
    s.x += a.x; s.y += a.y; s.z += a.z; s.w += a.w;
  }
  red[tid][0] = s.x; red[tid][1] = s.y;
  red[tid][2] = s.z; red[tid][3] = s.w;
  __syncthreads();

#pragma unroll
  for (int r = 0; r < 4; ++r) {
    const int slot = r * 256 + tid;
    const int hrow = slot >> 5;
    const int bseg = (slot & 31) * 8;
    bf16x8 v = *(const bf16x8*)(&asT[hrow][bseg]);
    *(bf16x8*)(&actT[(size_t)hrow * BATCH + b0 + bseg]) = v;
  }
  if (tid < 32) {
    const int q = tid >> 2, j = tid & 3;
    float t = 0.f;
#pragma unroll
    for (int sx = 0; sx < 32; ++sx) t += red[q + 8 * sx][j];
    actsum_part[blk * HID + tid] = t;
  }
}

// ---------------------------------------------------------------------------
// K1c: corr1T_part = x^T @ act (+ xsum via ones tile), reading xH bf16.
// 256-b chunks, C-reg accumulation over 4 halves (r21-verified).
// grid = 1024 = (bc 0..63 x 256 b) x (iq 0..15 x 128 i); 512 thr, (512,3).
// ---------------------------------------------------------------------------
__global__ __launch_bounds__(512, 3) void k_corr1(
    const unsigned short* __restrict__ xH,
    const unsigned short* __restrict__ actT,
    float* __restrict__ corr1T_part, float* __restrict__ xsum_part) {
  const int tid = threadIdx.x;
  const int bc = blockIdx.x >> 4;          // 0..63
  const int iq = blockIdx.x & 15;          // 0..15
  const int b0 = bc * 256;
  const int ibase = iq * 128;
  const int lane = tid & 63;
  const int wv = tid >> 6;                 // 0..7
  const int arow = lane & 15;
  const int m4 = lane >> 4;
  const int ksub = m4 * 8;
  const int it = wv * 16;                  // wave's i-tile base (0..112)

  __shared__ __align__(16) unsigned short XT[128 * SXT];   // [128 i][64 b]
  __shared__ __align__(16) unsigned short AT[48 * SAT2];   // [48][256 b]

  for (int e = tid; e < 16 * SAT2; e += 512)
    AT[32 * SAT2 + e] = (unsigned short)0x3F80;
  {
    const int hrow = tid >> 4;             // 0..31
    const int sg = (tid & 15) * 16;        // 0..240
    const int sw = ((hrow >> 3) & 7) * 8;
#pragma unroll
    for (int j = 0; j < 2; ++j) {
      const int boff = sg + 8 * j;
      bf16x8 v = *(const bf16x8*)(&actT[(size_t)hrow * BATCH + b0 + boff]);
      *(bf16x8*)(&AT[hrow * SAT2 + (boff ^ sw)]) = v;
    }
  }

  const int ig = tid & 15;                 // i-group (8 i)
  const int bq = tid >> 4;                 // 0..31 -> half-local rows 2bq,2bq+1

  bf16x8 xa, ya;

#define LOADC(HF)                                                           \
  {                                                                         \
    const int icol = ibase + ig * 8;                                        \
    const unsigned short* r0 =                                              \
        xH + (size_t)(b0 + 64 * (HF) + 2 * bq) * IND + icol;                \
    xa = *(const bf16x8*)(r0);                                              \
    ya = *(const bf16x8*)(r0 + IND);                                        \
  }

#define STC                                                                 \
  {                                                                         \
    const int qb = (2 * bq) ^ ((ig & 7) * 8);                               \
    unsigned short* basew = &XT[(size_t)(ig * 8) * SXT + qb];               \
    ushort2 p;                                                              \
    p.x = (unsigned short)xa[0]; p.y = (unsigned short)ya[0];               \
    *(ushort2*)(basew + 0 * SXT) = p;                                       \
    p.x = (unsigned short)xa[1]; p.y = (unsigned short)ya[1];               \
    *(ushort2*)(basew + 1 * SXT) = p;                                       \
    p.x = (unsigned short)xa[2]; p.y = (unsigned short)ya[2];               \
    *(ushort2*)(basew + 2 * SXT) = p;                                       \
    p.x = (unsigned short)xa[3]; p.y = (unsigned short)ya[3];               \
    *(ushort2*)(basew + 3 * SXT) = p;                                       \
    p.x = (unsigned short)xa[4]; p.y = (unsigned short)ya[4];               \
    *(ushort2*)(basew + 4 * SXT) = p;                                       \
    p.x = (unsigned short)xa[5]; p.y = (unsigned short)ya[5];               \
    *(ushort2*)(basew + 5 * SXT) = p;                                       \
    p.x = (unsigned short)xa[6]; p.y = (unsigned short)ya[6];               \
    *(ushort2*)(basew + 6 * SXT) = p;                                       \
    p.x = (unsigned short)xa[7]; p.y = (unsigned short)ya[7];               \
    *(ushort2*)(basew + 7 * SXT) = p;                                       \
  }

  const int swzr = (((it + arow) >> 3) & 7) * 8;
  const int swze0 = ((arow >> 3) & 7) * 8;
  const int swze1 = (((16 + arow) >> 3) & 7) * 8;

  f32x4 c00 = {0.f, 0.f, 0.f, 0.f};
  f32x4 c01 = {0.f, 0.f, 0.f, 0.f};
  f32x4 c02 = {0.f, 0.f, 0.f, 0.f};

  LOADC(0);
#pragma unroll
  for (int hf = 0; hf < 4; ++hf) {
    __syncthreads();
    STC;
    __syncthreads();
    if (hf < 3) LOADC(hf + 1);
#pragma unroll
    for (int bs = 0; bs < 2; ++bs) {
      const int bb = bs * 32 + ksub;
      const int bb2 = 64 * hf + bb;
      bf16x8 a = *(const bf16x8*)(&XT[(it + arow) * SXT + (bb ^ swzr)]);
      bf16x8 e0 = *(const bf16x8*)(&AT[arow * SAT2 + (bb2 ^ swze0)]);
      bf16x8 e1 = *(const bf16x8*)(&AT[(16 + arow) * SAT2 + (bb2 ^ swze1)]);
      bf16x8 e2 = *(const bf16x8*)(&AT[(32 + arow) * SAT2 + bb2]);
      c00 = __builtin_amdgcn_mfma_f32_16x16x32_bf16(a, e0, c00, 0, 0, 0);
      c01 = __builtin_amdgcn_mfma_f32_16x16x32_bf16(a, e1, c01, 0, 0, 0);
      c02 = __builtin_amdgcn_mfma_f32_16x16x32_bf16(a, e2, c02, 0, 0, 0);
    }
  }

  float* basep = corr1T_part + (size_t)bc * (IND * HID);
  const int gi = ibase + it + (m4 << 2);
  *(f32x4*)(basep + (size_t)arow * IND + gi) = c00;
  *(f32x4*)(basep + (size_t)(16 + arow) * IND + gi) = c01;
  if (arow == 0)
    *(f32x4*)(xsum_part + (size_t)bc * IND + gi) = c02;
}

// ---------------------------------------------------------------------------
// K3: MERGED k_fwd2m (blocks 0..511) + k_red1 (blocks 512..767). The two
// are data-independent (fwd2m <- actc/cvtw; red1 <- corr1/actc) but the
// single stream serialized them — grid-merging lets red1's 5us of streaming
// co-schedule under fwd2m's latency. Bodies r23-verbatim.
// ---------------------------------------------------------------------------
__global__ __launch_bounds__(256, 2) void k_fwd2m_red1(
    const unsigned short* __restrict__ actH,
    const unsigned short* __restrict__ actL,
    const unsigned short* __restrict__ actT,
    const unsigned short* __restrict__ w2H,
    const unsigned short* __restrict__ w2L,
    float* __restrict__ out, float* __restrict__ corr2_part,
    float* __restrict__ outsum_part,
    const float* __restrict__ c1p, const float* __restrict__ xsp,
    const float* __restrict__ asp,
    float* __restrict__ corr1T, float* __restrict__ xsum,
    float* __restrict__ actsum) {
  __shared__ __align__(16) unsigned short W2Hs[128 * 40];
  __shared__ __align__(16) unsigned short W2Ls[128 * 40];
  __shared__ __align__(16) unsigned short AH[64 * 40];
  __shared__ __align__(16) unsigned short AL[64 * 40];
  __shared__ __align__(16) unsigned short AT[48 * SATW];
  __shared__ __align__(16) unsigned short OT[128 * 72];

  const int tid = threadIdx.x;

  if (blockIdx.x >= 512) {  // ---------------- red1 body ----------------
    const int e = (blockIdx.x - 512) * 256 + tid;  // < 65536
    float s = 0.f;
#pragma unroll 8
    for (int c = 0; c < NC1; ++c) s += c1p[(size_t)c * (IND * HID) + e];
    corr1T[e] = s;
    if (e < IND) {
      float t = 0.f;
#pragma unroll 8
      for (int c = 0; c < NC1; ++c) t += xsp[(size_t)c * IND + e];
      xsum[e] = t;
    }
    if (e < HID) {
      float t = 0.f;
#pragma unroll 8
      for (int c = 0; c < NSA; ++c) t += asp[(size_t)c * HID + e];
      actsum[e] = t;
    }
    return;
  }

  // ---------------- fwd2m body (r23-verbatim) ----------------
  const int bc = blockIdx.x >> 2;          // 0..127
  const int og = blockIdx.x & 3;           // 0..3
  const int b0 = bc * 128;
  const int obase = og * 128;
  const int lane = tid & 63;
  const int wv = tid >> 6;                 // 0..3
  const int arow = lane & 15;
  const int m4 = lane >> 4;
  const int ksub = m4 * 8;

  {
    const int r2 = tid >> 1, hh = (tid & 1) * 16;
    const size_t wo = (size_t)(obase + r2) * HID + hh;
    *(bf16x8*)(&W2Hs[r2 * 40 + hh]) = *(const bf16x8*)(&w2H[wo]);
    *(bf16x8*)(&W2Hs[r2 * 40 + hh + 8]) = *(const bf16x8*)(&w2H[wo + 8]);
    *(bf16x8*)(&W2Ls[r2 * 40 + hh]) = *(const bf16x8*)(&w2L[wo]);
    *(bf16x8*)(&W2Ls[r2 * 40 + hh + 8]) = *(const bf16x8*)(&w2L[wo + 8]);
  }
  {
    const int h = tid >> 3, seg16 = (tid & 7) * 16;
#pragma unroll
    for (int j = 0; j < 2; ++j) {
      const int seg = seg16 + 8 * j;
      *(bf16x8*)(&AT[h * SATW + seg]) =
          *(const bf16x8*)(&actT[(size_t)h * BATCH + b0 + seg]);
    }
  }
  for (int e = tid; e < 16 * SATW; e += 256)
    AT[32 * SATW + e] = (unsigned short)0x3F80;

  f32x4 c0a = {0.f,0.f,0.f,0.f}, c1a = {0.f,0.f,0.f,0.f}, c2a = {0.f,0.f,0.f,0.f};
  f32x4 c0b = {0.f,0.f,0.f,0.f}, c1b = {0.f,0.f,0.f,0.f}, c2b = {0.f,0.f,0.f,0.f};

  for (int hf = 0; hf < 2; ++hf) {
    __syncthreads();
    {
      const int b = tid >> 2, q = (tid & 3) * 8;
      *(bf16x8*)(&AH[b * 40 + q]) =
          *(const bf16x8*)(&actH[(size_t)(b0 + 64 * hf + b) * HID + q]);
      *(bf16x8*)(&AL[b * 40 + q]) =
          *(const bf16x8*)(&actL[(size_t)(b0 + 64 * hf + b) * HID + q]);
    }
    __syncthreads();

    const int bt = wv;
    bf16x8 fah = *(const bf16x8*)(&AH[(bt * 16 + arow) * 40 + ksub]);
    bf16x8 fal = *(const bf16x8*)(&AL[(bt * 16 + arow) * 40 + ksub]);
#pragma unroll
    for (int ot = 0; ot < 8; ++ot) {
      bf16x8 wbh = *(const bf16x8*)(&W2Hs[(ot * 16 + arow) * 40 + ksub]);
      bf16x8 wbl = *(const bf16x8*)(&W2Ls[(ot * 16 + arow) * 40 + ksub]);
      f32x4 z = {0.f, 0.f, 0.f, 0.f};
      z = __builtin_amdgcn_mfma_f32_16x16x32_bf16(fah, wbh, z, 0, 0, 0);
      z = __builtin_amdgcn_mfma_f32_16x16x32_bf16(fah, wbl, z, 0, 0, 0);
      z = __builtin_amdgcn_mfma_f32_16x16x32_bf16(fal, wbh, z, 0, 0, 0);
      ushort4 po;
      {
        float ov0 = 1.0f / (1.0f + __expf(-z[0])) - 0.4f;
        float ov1 = 1.0f / (1.0f + __expf(-z[1])) - 0.4f;
        float ov2 = 1.0f / (1.0f + __expf(-z[2])) - 0.4f;
        float ov3 = 1.0f / (1.0f + __expf(-z[3])) - 0.4f;
        const size_t ob = (size_t)(b0 + 64 * hf + bt * 16 + m4 * 4) * OUTD +
                          obase + ot * 16 + arow;
        out[ob + 0 * OUTD] = ov0;
        out[ob + 1 * OUTD] = ov1;
        out[ob + 2 * OUTD] = ov2;
        out[ob + 3 * OUTD] = ov3;
        po.x = f2bf(ov0); po.y = f2bf(ov1); po.z = f2bf(ov2); po.w = f2bf(ov3);
      }
      *(ushort4*)(&OT[(ot * 16 + arow) * 72 + bt * 16 + m4 * 4]) = po;
    }
    __syncthreads();

    {
      const int ot = wv * 2;
#pragma unroll
      for (int ks = 0; ks < 2; ++ks) {
        const int bb = ks * 32 + ksub;
        const int bb2 = 64 * hf + bb;
        bf16x8 bo = *(const bf16x8*)(&OT[(ot * 16 + arow) * 72 + bb]);
        bf16x8 a0 = *(const bf16x8*)(&AT[arow * SATW + bb2]);
        bf16x8 a1 = *(const bf16x8*)(&AT[(16 + arow) * SATW + bb2]);
        bf16x8 a2 = *(const bf16x8*)(&AT[(32 + arow) * SATW + bb2]);
        c0a = __builtin_amdgcn_mfma_f32_16x16x32_bf16(a0, bo, c0a, 0, 0, 0);
        c1a = __builtin_amdgcn_mfma_f32_16x16x32_bf16(a1, bo, c1a, 0, 0, 0);
        c2a = __builtin_amdgcn_mfma_f32_16x16x32_bf16(a2, bo, c2a, 0, 0, 0);
      }
    }
    {
      const int ot = wv * 2 + 1;
#pragma unroll
      for (int ks = 0; ks < 2; ++ks) {
        const int bb = ks * 32 + ksub;
        const int bb2 = 64 * hf + bb;
        bf16x8 bo = *(const bf16x8*)(&OT[(ot * 16 + arow) * 72 + bb]);
        bf16x8 a0 = *(const bf16x8*)(&AT[arow * SATW + bb2]);
        bf16x8 a1 = *(const bf16x8*)(&AT[(16 + arow) * SATW + bb2]);
        bf16x8 a2 = *(const bf16x8*)(&AT[(32 + arow) * SATW + bb2]);
        c0b = __builtin_amdgcn_mfma_f32_16x16x32_bf16(a0, bo, c0b, 0, 0, 0);
        c1b = __builtin_amdgcn_mfma_f32_16x16x32_bf16(a1, bo, c1b, 0, 0, 0);
        c2b = __builtin_amdgcn_mfma_f32_16x16x32_bf16(a2, bo, c2b, 0, 0, 0);
      }
    }
  }

  {
    const int ot0 = wv * 2, ot1 = wv * 2 + 1;
    float* cp0 = corr2_part + (size_t)bc * (HID * OUTD) + obase + ot0 * 16 + arow;
    float* cp1 = corr2_part + (size_t)bc * (HID * OUTD) + obase + ot1 * 16 + arow;
#pragma unroll
    for (int r = 0; r < 4; ++r) {
      cp0[(size_t)(m4 * 4 + r) * OUTD] = c0a[r];
      cp0[(size_t)(16 + m4 * 4 + r) * OUTD] = c1a[r];
      cp1[(size_t)(m4 * 4 + r) * OUTD] = c0b[r];
      cp1[(size_t)(16 + m4 * 4 + r) * OUTD] = c1b[r];
    }
    if (m4 == 0) {
      outsum_part[(size_t)bc * OUTD + obase + ot0 * 16 + arow] = c2a[0];
      outsum_part[(size_t)bc * OUTD + obase + ot1 * 16 + arow] = c2b[0];
    }
  }
}

// ---------------------------------------------------------------------------
// K4: MERGED k_w1 (blocks 0..31) + k_red2 (blocks 32..95). Independent:
// w1 <- red1 outputs; red2 <- fwd2m outputs. Bodies r23-verbatim.
// ---------------------------------------------------------------------------
__global__ __launch_bounds__(256) void k_w1_red2(
    const float* __restrict__ w1, const float* __restrict__ heb,
    const float* __restrict__ corr1T, const float* __restrict__ xsum,
    const float* __restrict__ actsum, float* __restrict__ w1out,
    const float* __restrict__ corr2_part,
    const float* __restrict__ outsum_part,
    float* __restrict__ corr2, float* __restrict__ outsum) {
  const int tid = threadIdx.x;
  __shared__ float red[256];

  if (blockIdx.x >= 32) {  // ---------------- red2 body ----------------
    const int e = (blockIdx.x - 32) * 256 + tid;   // < 16384
    float s = 0.f;
#pragma unroll 8
    for (int c = 0; c < NC2; ++c) s += corr2_part[(size_t)c * (HID * OUTD) + e];
    corr2[e] = s;
    if (e < OUTD) {
      float t = 0.f;
#pragma unroll 8
      for (int c = 0; c < NC2; ++c) t += outsum_part[(size_t)c * OUTD + e];
      outsum[e] = t;
    }
    return;
  }

  // ---------------- w1 body ----------------
  const int h = blockIdx.x;
  const float ash = actsum[h];
  const float4* heb4 = (const float4*)heb;

  float val[8];
  float ss = 0.f;
#pragma unroll
  for (int r = 0; r < 8; ++r) {
    const int i = tid + 256 * r;
    float4 c = heb4[(size_t)i * HID + h];
    float v = w1[(size_t)h * IND + i] + 16384.0f * c.w +
              c.x * corr1T[(size_t)h * IND + i] + c.y * xsum[i] + c.z * ash;
    val[r] = v;
    ss += v * v;
  }

  red[tid] = ss;
  __syncthreads();
  for (int s = 128; s > 0; s >>= 1) {
    if (tid < s) red[tid] += red[tid + s];
    __syncthreads();
  }
  const float inv = 1.0f / sqrtf(red[0]);
#pragma unroll
  for (int r = 0; r < 8; ++r) {
    const int i = tid + 256 * r;
    w1out[(size_t)h * IND + i] = val[r] * inv;
  }
}

// ---------------------------------------------------------------------------
// K5: w2_new[o,h] = (w2[o,h] + dw2T[h,o]) / ||row o||_2
// ---------------------------------------------------------------------------
__global__ __launch_bounds__(256) void k_w2(
    const float* __restrict__ w2, const float* __restrict__ heb,
    const float* __restrict__ corr2, const float* __restrict__ actsum,
    const float* __restrict__ outsum, float* __restrict__ w2out) {
  const int o = blockIdx.x * 256 + threadIdx.x;
  const float oso = outsum[o];
  const float4* heb4 = (const float4*)heb;

  float val[HID];
  float ss = 0.f;
#pragma unroll
  for (int h = 0; h < HID; ++h) {
    float4 c = heb4[(size_t)(HID * IND) + (size_t)h * OUTD + o];
    float v = w2[(size_t)o * HID + h] + 16384.0f * c.w +
              c.x * corr2[(size_t)h * OUTD + o] + c.y * actsum[h] + c.z * oso;
    val[h] = v;
    ss += v * v;
  }
  const float inv = 1.0f / sqrtf(ss);
#pragma unroll
  for (int h = 0; h < HID; ++h) w2out[(size_t)o * HID + h] = val[h] * inv;
}

// ---------------------------------------------------------------------------
extern "C" void kernel_launch(void* const* d_in, const int* in_sizes, int n_in,
                              void* d_out, int out_size, void* d_ws,
                              size_t ws_size, hipStream_t stream) {
  const float* x   = (const float*)d_in[0];   // [16384, 2048]
  const float* w1  = (const float*)d_in[1];   // [32, 2048]
  const float* w2  = (const float*)d_in[2];   // [512, 32]
  const float* heb = (const float*)d_in[3];   // [81920, 4]

  float* out = (float*)d_out;                 // [16384, 512]
  float* w1o = out + (size_t)BATCH * OUTD;    // [32, 2048]
  float* w2o = w1o + (size_t)HID * IND;       // [512, 32]

  float* ws = (float*)d_ws;                   // ws ~537 MB; layout ~110 MB
  unsigned short* actH = (unsigned short*)ws;                      // 262144 f
  unsigned short* actL = actH + (size_t)BATCH * HID;               // 262144 f
  unsigned short* actT = actL + (size_t)BATCH * HID;               // 262144 f
  unsigned short* w1H  = actT + (size_t)BATCH * HID;               // 32768 f
  unsigned short* w1L  = w1H + (size_t)HID * IND;                  // 32768 f
  unsigned short* w2H  = w1L + (size_t)HID * IND;                  // 8192 f
  unsigned short* w2L  = w2H + (size_t)OUTD * HID;                 // 8192 f
  unsigned short* xH   = w2L + (size_t)OUTD * HID;                 // 33.5M us
  float* corr1T      = (float*)(xH + (size_t)BATCH * IND);         // 65536
  float* corr2       = corr1T + (size_t)IND * HID;                 // 16384
  float* xsum        = corr2 + (size_t)HID * OUTD;                 // 2048
  float* actsum      = xsum + IND;                                 // 32
  float* outsum      = actsum + HID;                               // 512
  float* act_part    = outsum + OUTD;                              // 2*524288
  float* corr1T_part = act_part + (size_t)2 * BATCH * HID;         // 64*65536
  float* xsum_part   = corr1T_part + (size_t)NC1 * IND * HID;      // 64*2048
  float* actsum_part = xsum_part + (size_t)NC1 * IND;              // 64*32
  float* corr2_part  = actsum_part + (size_t)NSA * HID;            // 128*16384
  float* outsum_part = corr2_part + (size_t)NC2 * HID * OUTD;      // 128*512

  k_cvtw      <<<80, 256, 0, stream>>>(w1, w2, w1H, w1L, w2H, w2L);
  k_act       <<<1024, 256, 0, stream>>>(x, w1H, w1L, act_part, xH);
  k_actc      <<<64, 256, 0, stream>>>(act_part, actH, actL, actT,
                                       actsum_part);
  k_corr1     <<<1024, 512, 0, stream>>>(xH, actT, corr1T_part, xsum_part);
  k_fwd2m_red1<<<768, 256, 0, stream>>>(actH, actL, actT, w2H, w2L, out,
                                        corr2_part, outsum_part,
                                        corr1T_part, xsum_part, actsum_part,
                                        corr1T, xsum, actsum);
  k_w1_red2   <<<96, 256, 0, stream>>>(w1, heb, corr1T, xsum, actsum, w1o,
                                       corr2_part, outsum_part, corr2,
                                       outsum);
  k_w2        <<<2, 256, 0, stream>>>(w2, heb, corr2, actsum, outsum, w2o);
}

// Round 25
// 98.885 us; speedup vs baseline: 1.4229x; 1.0794x over previous
//
#include <hip/hip_runtime.h>
#include <math.h>

// Problem constants
constexpr int BATCH = 16384;
constexpr int IND   = 2048;   // INPUT
constexpr int HID   = 32;     // HIDDEN
constexpr int OUTD  = 512;    // OUTPUT

constexpr int NC1 = 64;       // corr1/xsum partial slices (b-chunks of 256)
constexpr int NSA = 64;       // actsum partial slices (k_actc blocks)
constexpr int NC2 = 128;      // corr2/outsum partial slices (b-chunks of 128)

constexpr int SA   = 136;     // ushort row stride, k_act tiles
constexpr int SXT  = 72;      // ushort row stride, corr1 xT tile (64 b)
constexpr int SATW = 136;     // ushort row stride, fwd2m actT tile (128 b)
constexpr int SAT2 = 264;     // ushort row stride, corr1 actT tile (256 b)

typedef __attribute__((ext_vector_type(8))) short bf16x8;
typedef __attribute__((ext_vector_type(4))) float f32x4;

__device__ __forceinline__ unsigned short f2bf(float f) {
  unsigned u = __float_as_uint(f);
  u += 0x7FFFu + ((u >> 16) & 1u);          // round-to-nearest-even
  return (unsigned short)(u >> 16);
}
__device__ __forceinline__ float bf2f(unsigned short h) {
  return __uint_as_float(((unsigned)h) << 16);
}
__device__ __forceinline__ void split2(float f, unsigned short& hi,
                                       unsigned short& lo) {
  hi = f2bf(f);
  lo = f2bf(f - bf2f(hi));
}
__device__ __forceinline__ int swzA(int row, int col) {
  return row * SA + (col ^ (((row >> 3) & 7) * 8));
}

// ---------------------------------------------------------------------------
// K0: pre-split w1/w2 to hi/lo bf16 once (r19-verified).
// ---------------------------------------------------------------------------
__global__ __launch_bounds__(256) void k_cvtw(
    const float* __restrict__ w1, const float* __restrict__ w2,
    unsigned short* __restrict__ w1H, unsigned short* __restrict__ w1L,
    unsigned short* __restrict__ w2H, unsigned short* __restrict__ w2L) {
  const int bid = blockIdx.x;
  if (bid < 64) {
    const int g = bid * 256 + threadIdx.x;          // < 16384
    float4 v = ((const float4*)w1)[g];
    ushort4 h, l;
    split2(v.x, h.x, l.x); split2(v.y, h.y, l.y);
    split2(v.z, h.z, l.z); split2(v.w, h.w, l.w);
    ((ushort4*)w1H)[g] = h;
    ((ushort4*)w1L)[g] = l;
  } else {
    const int g = (bid - 64) * 256 + threadIdx.x;   // < 4096
    float4 v = ((const float4*)w2)[g];
    ushort4 h, l;
    split2(v.x, h.x, l.x); split2(v.y, h.y, l.y);
    split2(v.z, h.z, l.z); split2(v.w, h.w, l.w);
    ((ushort4*)w2H)[g] = h;
    ((ushort4*)w2L)[g] = l;
  }
}

// ---------------------------------------------------------------------------
// K1a: act partials = x @ w1T, split-bf16 MFMA; also emits xH bf16 [b][k]
// (r20-verified). grid = 1024 = (bt x 32 rows) x kq; (256,4).
// ---------------------------------------------------------------------------
__global__ __launch_bounds__(256, 4) void k_act(
    const float* __restrict__ x, const unsigned short* __restrict__ w1H,
    const unsigned short* __restrict__ w1L, float* __restrict__ act_part,
    unsigned short* __restrict__ xH) {
  const int tid = threadIdx.x;
  const int kq = blockIdx.x & 1;
  const int bt = blockIdx.x >> 1;          // 0..511
  const int b0 = bt * 32;
  const int kbase = kq * 1024;
  const int lane = tid & 63;
  const int wv = tid >> 6;                 // 0..3
  const int arow = lane & 15;
  const int m4 = lane >> 4;                // 0..3
  const int ksub = m4 * 8;
  const int rt = wv & 1;
  const int ht = wv >> 1;

  __shared__ __align__(16) unsigned short XH[32 * SA];
  __shared__ __align__(16) unsigned short XL[32 * SA];
  __shared__ __align__(16) unsigned short WH[32 * SA];
  __shared__ __align__(16) unsigned short WL[32 * SA];

  const int rp = tid >> 4;
  const int kg = (tid & 15) * 8;

  float4 px0a, px0b, px1a, px1b;
  bf16x8 pwh0, pwl0, pwh1, pwl1;

#define LOADA(K0)                                                          \
  {                                                                        \
    const float* xr0 = x + (size_t)(b0 + 2 * rp) * IND + kbase + (K0) + kg;\
    const float* xr1 = xr0 + IND;                                          \
    px0a = *(const float4*)(xr0);                                          \
    px0b = *(const float4*)(xr0 + 4);                                      \
    px1a = *(const float4*)(xr1);                                          \
    px1b = *(const float4*)(xr1 + 4);                                      \
    const size_t wo = (size_t)(2 * rp) * IND + kbase + (K0) + kg;          \
    pwh0 = *(const bf16x8*)(&w1H[wo]);                                     \
    pwl0 = *(const bf16x8*)(&w1L[wo]);                                     \
    pwh1 = *(const bf16x8*)(&w1H[wo + IND]);                               \
    pwl1 = *(const bf16x8*)(&w1L[wo + IND]);                               \
  }

#define PUTX2(ROW, COL, V, GK)                                       \
  {                                                                  \
    ushort4 h_, l_;                                                  \
    split2((V).x, h_.x, l_.x); split2((V).y, h_.y, l_.y);            \
    split2((V).z, h_.z, l_.z); split2((V).w, h_.w, l_.w);            \
    *(ushort4*)(&XH[swzA((ROW), (COL))]) = h_;                       \
    *(ushort4*)(&XL[swzA((ROW), (COL))]) = l_;                       \
    *(ushort4*)(&xH[(size_t)(b0 + (ROW)) * IND + (GK) + (COL)]) = h_;\
  }

#define STOREA(GK)                                                   \
  {                                                                  \
    PUTX2(2 * rp, kg, px0a, GK);                                     \
    PUTX2(2 * rp, kg + 4, px0b, GK);                                 \
    PUTX2(2 * rp + 1, kg, px1a, GK);                                 \
    PUTX2(2 * rp + 1, kg + 4, px1b, GK);                             \
    *(bf16x8*)(&WH[swzA(2 * rp, kg)]) = pwh0;                        \
    *(bf16x8*)(&WL[swzA(2 * rp, kg)]) = pwl0;                        \
    *(bf16x8*)(&WH[swzA(2 * rp + 1, kg)]) = pwh1;                    \
    *(bf16x8*)(&WL[swzA(2 * rp + 1, kg)]) = pwl1;                    \
  }

  f32x4 accA = {0.f, 0.f, 0.f, 0.f};
  LOADA(0);

  for (int kc = 0; kc < 8; ++kc) {
    __syncthreads();
    STOREA(kbase + kc * 128);
    __syncthreads();
    if (kc < 7) LOADA((kc + 1) * 128);
    const int xrow = rt * 16 + arow;
    const int wrow = ht * 16 + arow;
#pragma unroll
    for (int ks = 0; ks < 4; ++ks) {
      const int kk = ks * 32 + ksub;
      bf16x8 ah = *(const bf16x8*)(&XH[swzA(xrow, kk)]);
      bf16x8 al = *(const bf16x8*)(&XL[swzA(xrow, kk)]);
      bf16x8 bh = *(const bf16x8*)(&WH[swzA(wrow, kk)]);
      bf16x8 bl_ = *(const bf16x8*)(&WL[swzA(wrow, kk)]);
      accA = __builtin_amdgcn_mfma_f32_16x16x32_bf16(ah, bh, accA, 0, 0, 0);
      accA = __builtin_amdgcn_mfma_f32_16x16x32_bf16(ah, bl_, accA, 0, 0, 0);
      accA = __builtin_amdgcn_mfma_f32_16x16x32_bf16(al, bh, accA, 0, 0, 0);
    }
  }

  const int bl = rt * 16 + (m4 << 2);
  const int h = ht * 16 + arow;
  float* p = act_part + (size_t)kq * (BATCH * HID);
#pragma unroll
  for (int r = 0; r < 4; ++r)
    p[(size_t)(b0 + bl + r) * HID + h] = accA[r];
}

// ---------------------------------------------------------------------------
// K1b: combine K-half partials -> relu -> actH/actL [b][h] + actT [h][b] +
// actsum partials (r19-verbatim). grid = 64 x 256.
// ---------------------------------------------------------------------------
__global__ __launch_bounds__(256) void k_actc(
    const float* __restrict__ act_part,
    unsigned short* __restrict__ actH, unsigned short* __restrict__ actL,
    unsigned short* __restrict__ actT, float* __restrict__ actsum_part) {
  const int tid = threadIdx.x;
  const int blk = blockIdx.x;              // 0..63
  const int b0 = blk * 256;

  __shared__ unsigned short asT[32][264];
  __shared__ float red[256][4];

  const float4* p0 = (const float4*)act_part;
  const float4* p1 = p0 + (size_t)BATCH * HID / 4;

  const int hq = tid & 7;
  float4 s{0.f, 0.f, 0.f, 0.f};
#pragma unroll
  for (int r = 0; r < 8; ++r) {
    const int e4 = r * 256 + tid;
    const int b = e4 >> 3;
    const size_t g = (size_t)(b0 + b) * 8 + hq;
    float4 a = p0[g];
    float4 c = p1[g];
    a.x = fmaxf(a.x + c.x, 0.f);  a.y = fmaxf(a.y + c.y, 0.f);
    a.z = fmaxf(a.z + c.z, 0.f);  a.w = fmaxf(a.w + c.w, 0.f);
    ushort4 hh, ll;
    split2(a.x, hh.x, ll.x); split2(a.y, hh.y, ll.y);
    split2(a.z, hh.z, ll.z); split2(a.w, hh.w, ll.w);
    *(ushort4*)(&actH[g * 4]) = hh;
    *(ushort4*)(&actL[g * 4]) = ll;
    asT[hq * 4 + 0][b] = hh.x;
    asT[hq * 4 + 1][b] = hh.y;
    asT[hq * 4 + 2][b] = hh.z;
    asT[hq * 4 + 3][b] = hh.w;
    s.x += a.x; s.y += a.y; s.z += a.z; s.w += a.w;
  }
  red[tid][0] = s.x; red[tid][1] = s.y;
  red[tid][2] = s.z; red[tid][3] = s.w;
  __syncthreads();

#pragma unroll
  for (int r = 0; r < 4; ++r) {
    const int slot = r * 256 + tid;
    const int hrow = slot >> 5;
    const int bseg = (slot & 31) * 8;
    bf16x8 v = *(const bf16x8*)(&asT[hrow][bseg]);
    *(bf16x8*)(&actT[(size_t)hrow * BATCH + b0 + bseg]) = v;
  }
  if (tid < 32) {
    const int q = tid >> 2, j = tid & 3;
    float t = 0.f;
#pragma unroll
    for (int sx = 0; sx < 32; ++sx) t += red[q + 8 * sx][j];
    actsum_part[blk * HID + tid] = t;
  }
}

// ---------------------------------------------------------------------------
// K2: MERGED corr1 (blocks 0..1023, 512 thr) + fwd2m (blocks 1024..1535,
// 256 active of 512; barriers uniform). The two are data-independent
// (corr1 <- xH/actT; fwd2m <- actH/L/T, w2H/L) but were serialized.
// LDS unioned (57.9KB arena, paths disjoint per block); both AT tiles
// shrunk 48->32 rows: all-ones B-fragment now a register constant
// (bitwise-identical MFMA input). Bodies otherwise r24-verbatim.
// ---------------------------------------------------------------------------
__global__ __launch_bounds__(512, 2) void k_corr1_fwd2m(
    const unsigned short* __restrict__ xH,
    const unsigned short* __restrict__ actT,
    float* __restrict__ corr1T_part, float* __restrict__ xsum_part,
    const unsigned short* __restrict__ actH,
    const unsigned short* __restrict__ actL,
    const unsigned short* __restrict__ w2H,
    const unsigned short* __restrict__ w2L,
    float* __restrict__ out, float* __restrict__ corr2_part,
    float* __restrict__ outsum_part) {
  __shared__ __align__(16) char smem[57856];
  const int tid = threadIdx.x;
  const short ob = (short)0x3F80;
  const bf16x8 ones = {ob, ob, ob, ob, ob, ob, ob, ob};

  if (blockIdx.x < 1024) {
    // ---------------- corr1 body ----------------
    unsigned short* const XT = (unsigned short*)smem;            // 128 x SXT
    unsigned short* const AT = (unsigned short*)(smem + 18432);  // 32 x SAT2

    const int bc = blockIdx.x >> 4;        // 0..63
    const int iq = blockIdx.x & 15;        // 0..15
    const int b0 = bc * 256;
    const int ibase = iq * 128;
    const int lane = tid & 63;
    const int wv = tid >> 6;               // 0..7
    const int arow = lane & 15;
    const int m4 = lane >> 4;
    const int ksub = m4 * 8;
    const int it = wv * 16;

    {
      const int hrow = tid >> 4;           // 0..31
      const int sg = (tid & 15) * 16;      // 0..240
      const int sw = ((hrow >> 3) & 7) * 8;
#pragma unroll
      for (int j = 0; j < 2; ++j) {
        const int boff = sg + 8 * j;
        bf16x8 v = *(const bf16x8*)(&actT[(size_t)hrow * BATCH + b0 + boff]);
        *(bf16x8*)(&AT[hrow * SAT2 + (boff ^ sw)]) = v;
      }
    }

    const int ig = tid & 15;               // i-group (8 i)
    const int bq = tid >> 4;               // 0..31

    bf16x8 xa, ya;

#define LOADC(HF)                                                           \
  {                                                                         \
    const int icol = ibase + ig * 8;                                        \
    const unsigned short* r0 =                                              \
        xH + (size_t)(b0 + 64 * (HF) + 2 * bq) * IND + icol;                \
    xa = *(const bf16x8*)(r0);                                              \
    ya = *(const bf16x8*)(r0 + IND);                                        \
  }

#define STC                                                                 \
  {                                                                         \
    const int qb = (2 * bq) ^ ((ig & 7) * 8);                               \
    unsigned short* basew = &XT[(size_t)(ig * 8) * SXT + qb];               \
    ushort2 p;                                                              \
    p.x = (unsigned short)xa[0]; p.y = (unsigned short)ya[0];               \
    *(ushort2*)(basew + 0 * SXT) = p;                                       \
    p.x = (unsigned short)xa[1]; p.y = (unsigned short)ya[1];               \
    *(ushort2*)(basew + 1 * SXT) = p;                                       \
    p.x = (unsigned short)xa[2]; p.y = (unsigned short)ya[2];               \
    *(ushort2*)(basew + 2 * SXT) = p;                                       \
    p.x = (unsigned short)xa[3]; p.y = (unsigned short)ya[3];               \
    *(ushort2*)(basew + 3 * SXT) = p;                                       \
    p.x = (unsigned short)xa[4]; p.y = (unsigned short)ya[4];               \
    *(ushort2*)(basew + 4 * SXT) = p;                                       \
    p.x = (unsigned short)xa[5]; p.y = (unsigned short)ya[5];               \
    *(ushort2*)(basew + 5 * SXT) = p;                                       \
    p.x = (unsigned short)xa[6]; p.y = (unsigned short)ya[6];               \
    *(ushort2*)(basew + 6 * SXT) = p;                                       \
    p.x = (unsigned short)xa[7]; p.y = (unsigned short)ya[7];               \
    *(ushort2*)(basew + 7 * SXT) = p;                                       \
  }

    const int swzr = (((it + arow) >> 3) & 7) * 8;
    const int swze0 = ((arow >> 3) & 7) * 8;
    const int swze1 = (((16 + arow) >> 3) & 7) * 8;

    f32x4 c00 = {0.f, 0.f, 0.f, 0.f};
    f32x4 c01 = {0.f, 0.f, 0.f, 0.f};
    f32x4 c02 = {0.f, 0.f, 0.f, 0.f};

    LOADC(0);
#pragma unroll
    for (int hf = 0; hf < 4; ++hf) {
      __syncthreads();
      STC;
      __syncthreads();
      if (hf < 3) LOADC(hf + 1);
#pragma unroll
      for (int bs = 0; bs < 2; ++bs) {
        const int bb = bs * 32 + ksub;
        const int bb2 = 64 * hf + bb;
        bf16x8 a = *(const bf16x8*)(&XT[(it + arow) * SXT + (bb ^ swzr)]);
        bf16x8 e0 = *(const bf16x8*)(&AT[arow * SAT2 + (bb2 ^ swze0)]);
        bf16x8 e1 = *(const bf16x8*)(&AT[(16 + arow) * SAT2 + (bb2 ^ swze1)]);
        c00 = __builtin_amdgcn_mfma_f32_16x16x32_bf16(a, e0, c00, 0, 0, 0);
        c01 = __builtin_amdgcn_mfma_f32_16x16x32_bf16(a, e1, c01, 0, 0, 0);
        c02 = __builtin_amdgcn_mfma_f32_16x16x32_bf16(a, ones, c02, 0, 0, 0);
      }
    }

    float* basep = corr1T_part + (size_t)bc * (IND * HID);
    const int gi = ibase + it + (m4 << 2);
    *(f32x4*)(basep + (size_t)arow * IND + gi) = c00;
    *(f32x4*)(basep + (size_t)(16 + arow) * IND + gi) = c01;
    if (arow == 0)
      *(f32x4*)(xsum_part + (size_t)bc * IND + gi) = c02;
    return;
  }

  // ---------------- fwd2m body (256 active threads) ----------------
  unsigned short* const W2Hs = (unsigned short*)smem;            // 128 x 40
  unsigned short* const W2Ls = (unsigned short*)(smem + 10240);
  unsigned short* const AH   = (unsigned short*)(smem + 20480);  // 64 x 40
  unsigned short* const AL   = (unsigned short*)(smem + 25600);
  unsigned short* const AT2  = (unsigned short*)(smem + 30720);  // 32 x SATW
  unsigned short* const OT   = (unsigned short*)(smem + 39424);  // 128 x 72

  const bool on = tid < 256;
  const int bidx = blockIdx.x - 1024;      // 0..511
  const int bc = bidx >> 2;                // 0..127
  const int og = bidx & 3;                 // 0..3
  const int b0 = bc * 128;
  const int obase = og * 128;
  const int lane = tid & 63;
  const int wv = (tid >> 6) & 3;           // 0..3 (waves 4..7 idle-mirror)
  const int arow = lane & 15;
  const int m4 = lane >> 4;
  const int ksub = m4 * 8;

  if (on) {
    const int r2 = tid >> 1, hh = (tid & 1) * 16;
    const size_t wo = (size_t)(obase + r2) * HID + hh;
    *(bf16x8*)(&W2Hs[r2 * 40 + hh]) = *(const bf16x8*)(&w2H[wo]);
    *(bf16x8*)(&W2Hs[r2 * 40 + hh + 8]) = *(const bf16x8*)(&w2H[wo + 8]);
    *(bf16x8*)(&W2Ls[r2 * 40 + hh]) = *(const bf16x8*)(&w2L[wo]);
    *(bf16x8*)(&W2Ls[r2 * 40 + hh + 8]) = *(const bf16x8*)(&w2L[wo + 8]);
    const int h = tid >> 3, seg16 = (tid & 7) * 16;
#pragma unroll
    for (int j = 0; j < 2; ++j) {
      const int seg = seg16 + 8 * j;
      *(bf16x8*)(&AT2[h * SATW + seg]) =
          *(const bf16x8*)(&actT[(size_t)h * BATCH + b0 + seg]);
    }
  }

  f32x4 c0a = {0.f,0.f,0.f,0.f}, c1a = {0.f,0.f,0.f,0.f}, c2a = {0.f,0.f,0.f,0.f};
  f32x4 c0b = {0.f,0.f,0.f,0.f}, c1b = {0.f,0.f,0.f,0.f}, c2b = {0.f,0.f,0.f,0.f};

  for (int hf = 0; hf < 2; ++hf) {
    __syncthreads();
    if (on) {
      const int b = tid >> 2, q = (tid & 3) * 8;
      *(bf16x8*)(&AH[b * 40 + q]) =
          *(const bf16x8*)(&actH[(size_t)(b0 + 64 * hf + b) * HID + q]);
      *(bf16x8*)(&AL[b * 40 + q]) =
          *(const bf16x8*)(&actL[(size_t)(b0 + 64 * hf + b) * HID + q]);
    }
    __syncthreads();

    if (on) {
      const int bt = wv;
      bf16x8 fah = *(const bf16x8*)(&AH[(bt * 16 + arow) * 40 + ksub]);
      bf16x8 fal = *(const bf16x8*)(&AL[(bt * 16 + arow) * 40 + ksub]);
#pragma unroll
      for (int ot = 0; ot < 8; ++ot) {
        bf16x8 wbh = *(const bf16x8*)(&W2Hs[(ot * 16 + arow) * 40 + ksub]);
        bf16x8 wbl = *(const bf16x8*)(&W2Ls[(ot * 16 + arow) * 40 + ksub]);
        f32x4 z = {0.f, 0.f, 0.f, 0.f};
        z = __builtin_amdgcn_mfma_f32_16x16x32_bf16(fah, wbh, z, 0, 0, 0);
        z = __builtin_amdgcn_mfma_f32_16x16x32_bf16(fah, wbl, z, 0, 0, 0);
        z = __builtin_amdgcn_mfma_f32_16x16x32_bf16(fal, wbh, z, 0, 0, 0);
        ushort4 po;
        {
          float ov0 = 1.0f / (1.0f + __expf(-z[0])) - 0.4f;
          float ov1 = 1.0f / (1.0f + __expf(-z[1])) - 0.4f;
          float ov2 = 1.0f / (1.0f + __expf(-z[2])) - 0.4f;
          float ov3 = 1.0f / (1.0f + __expf(-z[3])) - 0.4f;
          const size_t obp = (size_t)(b0 + 64 * hf + bt * 16 + m4 * 4) * OUTD +
                             obase + ot * 16 + arow;
          out[obp + 0 * OUTD] = ov0;
          out[obp + 1 * OUTD] = ov1;
          out[obp + 2 * OUTD] = ov2;
          out[obp + 3 * OUTD] = ov3;
          po.x = f2bf(ov0); po.y = f2bf(ov1);
          po.z = f2bf(ov2); po.w = f2bf(ov3);
        }
        *(ushort4*)(&OT[(ot * 16 + arow) * 72 + bt * 16 + m4 * 4]) = po;
      }
    }
    __syncthreads();

    if (on) {
      {
        const int ot = wv * 2;
#pragma unroll
        for (int ks = 0; ks < 2; ++ks) {
          const int bb = ks * 32 + ksub;
          const int bb2 = 64 * hf + bb;
          bf16x8 bo = *(const bf16x8*)(&OT[(ot * 16 + arow) * 72 + bb]);
          bf16x8 a0 = *(const bf16x8*)(&AT2[arow * SATW + bb2]);
          bf16x8 a1 = *(const bf16x8*)(&AT2[(16 + arow) * SATW + bb2]);
          c0a = __builtin_amdgcn_mfma_f32_16x16x32_bf16(a0, bo, c0a, 0, 0, 0);
          c1a = __builtin_amdgcn_mfma_f32_16x16x32_bf16(a1, bo, c1a, 0, 0, 0);
          c2a = __builtin_amdgcn_mfma_f32_16x16x32_bf16(ones, bo, c2a, 0, 0, 0);
        }
      }
      {
        const int ot = wv * 2 + 1;
#pragma unroll
        for (int ks = 0; ks < 2; ++ks) {
          const int bb = ks * 32 + ksub;
          const int bb2 = 64 * hf + bb;
          bf16x8 bo = *(const bf16x8*)(&OT[(ot * 16 + arow) * 72 + bb]);
          bf16x8 a0 = *(const bf16x8*)(&AT2[arow * SATW + bb2]);
          bf16x8 a1 = *(const bf16x8*)(&AT2[(16 + arow) * SATW + bb2]);
          c0b = __builtin_amdgcn_mfma_f32_16x16x32_bf16(a0, bo, c0b, 0, 0, 0);
          c1b = __builtin_amdgcn_mfma_f32_16x16x32_bf16(a1, bo, c1b, 0, 0, 0);
          c2b = __builtin_amdgcn_mfma_f32_16x16x32_bf16(ones, bo, c2b, 0, 0, 0);
        }
      }
    }
  }

  if (on) {
    const int ot0 = wv * 2, ot1 = wv * 2 + 1;
    float* cp0 = corr2_part + (size_t)bc * (HID * OUTD) + obase + ot0 * 16 + arow;
    float* cp1 = corr2_part + (size_t)bc * (HID * OUTD) + obase + ot1 * 16 + arow;
#pragma unroll
    for (int r = 0; r < 4; ++r) {
      cp0[(size_t)(m4 * 4 + r) * OUTD] = c0a[r];
      cp0[(size_t)(16 + m4 * 4 + r) * OUTD] = c1a[r];
      cp1[(size_t)(m4 * 4 + r) * OUTD] = c0b[r];
      cp1[(size_t)(16 + m4 * 4 + r) * OUTD] = c1b[r];
    }
    if (m4 == 0) {
      outsum_part[(size_t)bc * OUTD + obase + ot0 * 16 + arow] = c2a[0];
      outsum_part[(size_t)bc * OUTD + obase + ot1 * 16 + arow] = c2b[0];
    }
  }
}

// ---------------------------------------------------------------------------
// K3: MERGED red1 (blocks 0..255) + red2 (blocks 256..319). Both inputs
// ready after k_corr1_fwd2m. Bodies r24-verbatim.
// ---------------------------------------------------------------------------
__global__ __launch_bounds__(256) void k_red12(
    const float* __restrict__ c1p, const float* __restrict__ xsp,
    const float* __restrict__ asp,
    float* __restrict__ corr1T, float* __restrict__ xsum,
    float* __restrict__ actsum,
    const float* __restrict__ corr2_part,
    const float* __restrict__ outsum_part,
    float* __restrict__ corr2, float* __restrict__ outsum) {
  const int tid = threadIdx.x;
  if (blockIdx.x >= 256) {   // red2
    const int e = (blockIdx.x - 256) * 256 + tid;  // < 16384
    float s = 0.f;
#pragma unroll 8
    for (int c = 0; c < NC2; ++c) s += corr2_part[(size_t)c * (HID * OUTD) + e];
    corr2[e] = s;
    if (e < OUTD) {
      float t = 0.f;
#pragma unroll 8
      for (int c = 0; c < NC2; ++c) t += outsum_part[(size_t)c * OUTD + e];
      outsum[e] = t;
    }
    return;
  }
  // red1
  const int e = blockIdx.x * 256 + tid;    // < 65536
  float s = 0.f;
#pragma unroll 8
  for (int c = 0; c < NC1; ++c) s += c1p[(size_t)c * (IND * HID) + e];
  corr1T[e] = s;
  if (e < IND) {
    float t = 0.f;
#pragma unroll 8
    for (int c = 0; c < NC1; ++c) t += xsp[(size_t)c * IND + e];
    xsum[e] = t;
  }
  if (e < HID) {
    float t = 0.f;
#pragma unroll 8
    for (int c = 0; c < NSA; ++c) t += asp[(size_t)c * HID + e];
    actsum[e] = t;
  }
}

// ---------------------------------------------------------------------------
// K4: MERGED w1 (blocks 0..31) + w2 (blocks 32..33). Both inputs ready
// after k_red12. Bodies r24-verbatim.
// ---------------------------------------------------------------------------
__global__ __launch_bounds__(256) void k_w12(
    const float* __restrict__ w1, const float* __restrict__ heb,
    const float* __restrict__ corr1T, const float* __restrict__ xsum,
    const float* __restrict__ actsum, float* __restrict__ w1out,
    const float* __restrict__ w2, const float* __restrict__ corr2,
    const float* __restrict__ outsum, float* __restrict__ w2out) {
  const int tid = threadIdx.x;
  __shared__ float red[256];

  if (blockIdx.x >= 32) {    // w2 body
    const int o = (blockIdx.x - 32) * 256 + tid;   // < 512
    const float oso = outsum[o];
    const float4* heb4 = (const float4*)heb;
    float val[HID];
    float ss = 0.f;
#pragma unroll
    for (int h = 0; h < HID; ++h) {
      float4 c = heb4[(size_t)(HID * IND) + (size_t)h * OUTD + o];
      float v = w2[(size_t)o * HID + h] + 16384.0f * c.w +
                c.x * corr2[(size_t)h * OUTD + o] + c.y * actsum[h] + c.z * oso;
      val[h] = v;
      ss += v * v;
    }
    const float inv = 1.0f / sqrtf(ss);
#pragma unroll
    for (int h = 0; h < HID; ++h) w2out[(size_t)o * HID + h] = val[h] * inv;
    return;
  }

  // w1 body
  const int h = blockIdx.x;
  const float ash = actsum[h];
  const float4* heb4 = (const float4*)heb;
  float val[8];
  float ss = 0.f;
#pragma unroll
  for (int r = 0; r < 8; ++r) {
    const int i = tid + 256 * r;
    float4 c = heb4[(size_t)i * HID + h];
    float v = w1[(size_t)h * IND + i] + 16384.0f * c.w +
              c.x * corr1T[(size_t)h * IND + i] + c.y * xsum[i] + c.z * ash;
    val[r] = v;
    ss += v * v;
  }
  red[tid] = ss;
  __syncthreads();
  for (int s = 128; s > 0; s >>= 1) {
    if (tid < s) red[tid] += red[tid + s];
    __syncthreads();
  }
  const float inv = 1.0f / sqrtf(red[0]);
#pragma unroll
  for (int r = 0; r < 8; ++r) {
    const int i = tid + 256 * r;
    w1out[(size_t)h * IND + i] = val[r] * inv;
  }
}

// ---------------------------------------------------------------------------
extern "C" void kernel_launch(void* const* d_in, const int* in_sizes, int n_in,
                              void* d_out, int out_size, void* d_ws,
                              size_t ws_size, hipStream_t stream) {
  const float* x   = (const float*)d_in[0];   // [16384, 2048]
  const float* w1  = (const float*)d_in[1];   // [32, 2048]
  const float* w2  = (const float*)d_in[2];   // [512, 32]
  const float* heb = (const float*)d_in[3];   // [81920, 4]

  float* out = (float*)d_out;                 // [16384, 512]
  float* w1o = out + (size_t)BATCH * OUTD;    // [32, 2048]
  float* w2o = w1o + (size_t)HID * IND;       // [512, 32]

  float* ws = (float*)d_ws;                   // ws ~537 MB; layout ~110 MB
  unsigned short* actH = (unsigned short*)ws;                      // 262144 f
  unsigned short* actL = actH + (size_t)BATCH * HID;               // 262144 f
  unsigned short* actT = actL + (size_t)BATCH * HID;               // 262144 f
  unsigned short* w1H  = actT + (size_t)BATCH * HID;               // 32768 f
  unsigned short* w1L  = w1H + (size_t)HID * IND;                  // 32768 f
  unsigned short* w2H  = w1L + (size_t)HID * IND;                  // 8192 f
  unsigned short* w2L  = w2H + (size_t)OUTD * HID;                 // 8192 f
  unsigned short* xH   = w2L + (size_t)OUTD * HID;                 // 33.5M us
  float* corr1T      = (float*)(xH + (size_t)BATCH * IND);         // 65536
  float* corr2       = corr1T + (size_t)IND * HID;                 // 16384
  float* xsum        = corr2 + (size_t)HID * OUTD;                 // 2048
  float* actsum      = xsum + IND;                                 // 32
  float* outsum      = actsum + HID;                               // 512
  float* act_part    = outsum + OUTD;                              // 2*524288
  float* corr1T_part = act_part + (size_t)2 * BATCH * HID;         // 64*65536
  float* xsum_part   = corr1T_part + (size_t)NC1 * IND * HID;      // 64*2048
  float* actsum_part = xsum_part + (size_t)NC1 * IND;              // 64*32
  float* corr2_part  = actsum_part + (size_t)NSA * HID;            // 128*16384
  float* outsum_part = corr2_part + (size_t)NC2 * HID * OUTD;      // 128*512

  k_cvtw       <<<80, 256, 0, stream>>>(w1, w2, w1H, w1L, w2H, w2L);
  k_act        <<<1024, 256, 0, stream>>>(x, w1H, w1L, act_part, xH);
  k_actc       <<<64, 256, 0, stream>>>(act_part, actH, actL, actT,
                                        actsum_part);
  k_corr1_fwd2m<<<1536, 512, 0, stream>>>(xH, actT, corr1T_part, xsum_part,
                                          actH, actL, w2H, w2L, out,
                                          corr2_part, outsum_part);
  k_red12      <<<320, 256, 0, stream>>>(corr1T_part, xsum_part, actsum_part,
                                         corr1T, xsum, actsum,
                                         corr2_part, outsum_part, corr2,
                                         outsum);
  k_w12        <<<34, 256, 0, stream>>>(w1, heb, corr1T, xsum, actsum, w1o,
                                        w2, corr2, outsum, w2o);
}